// Round 1
// baseline (4584.274 us; speedup 1.0000x reference)
//
#include <hip/hip_runtime.h>
#include <hip/hip_bf16.h>

#define B 512
#define N 207
#define C 207
#define C3 621
#define CO 512
#define NLAYERS 2
#define EPS 1e-5f

typedef __hip_bfloat16 bf16;

__device__ __forceinline__ float b2f(bf16 v){ return __bfloat162float(v); }
__device__ __forceinline__ bf16 f2b(float v){ return __float2bfloat16(v); }

// ---------------------------------------------------------------------------
// adp row softmax: A[v][w] = adp[w][v] = softmax_j(relu(nv1[w,:]@nv2[:,j]))[v]
// one block per row w of adp
// ---------------------------------------------------------------------------
__global__ void adp_kernel(const float* __restrict__ nv1, const float* __restrict__ nv2,
                           float* __restrict__ A) {
    int w = blockIdx.x;
    int j = threadIdx.x;
    __shared__ float red[256];
    float val = 0.f;
    float s = -1e30f;
    if (j < N) {
        float acc = 0.f;
        #pragma unroll
        for (int k = 0; k < 10; ++k) acc += nv1[w*10 + k] * nv2[k*N + j];
        val = fmaxf(acc, 0.f);
        s = val;
    }
    red[j] = s;
    __syncthreads();
    for (int off = 128; off > 0; off >>= 1) {
        if (j < off) red[j] = fmaxf(red[j], red[j+off]);
        __syncthreads();
    }
    float m = red[0];
    __syncthreads();
    float e = (j < N) ? expf(val - m) : 0.f;
    red[j] = e;
    __syncthreads();
    for (int off = 128; off > 0; off >>= 1) {
        if (j < off) red[j] += red[j+off];
        __syncthreads();
    }
    float inv = 1.f / red[0];
    if (j < N) A[j*N + w] = e * inv;   // transposed store: A = adp^T
}

// A2 = A @ A  (tiny: 207^3 FMA)
__global__ void a2_kernel(const float* __restrict__ A, float* __restrict__ A2) {
    int w = blockIdx.x*16 + threadIdx.x;
    int v = blockIdx.y*16 + threadIdx.y;
    if (v < N && w < N) {
        float acc = 0.f;
        for (int k = 0; k < N; ++k) acc += A[v*N + k] * A[k*N + w];
        A2[v*N + w] = acc;
    }
}

// BN fold: inv = gamma*rsqrt(rvar+eps); shift = beta - rmean*inv
__global__ void bn_kernel(const float* __restrict__ gamma, const float* __restrict__ beta,
                          const float* __restrict__ rmean, const float* __restrict__ rvar,
                          float* __restrict__ binv, float* __restrict__ bshift) {
    int i = blockIdx.x*256 + threadIdx.x;
    if (i < NLAYERS*C) {
        float iv = gamma[i] * rsqrtf(rvar[i] + EPS);
        binv[i] = iv;
        bshift[i] = beta[i] - rmean[i]*iv;
    }
}

// transpose x (B,N,C) f32 -> H (B,C,N) bf16
__global__ void transpose_kernel(const float* __restrict__ x, bf16* __restrict__ H) {
    __shared__ float t[32][33];
    int b = blockIdx.z;
    int n0 = blockIdx.x*32, c0 = blockIdx.y*32;
    for (int i = threadIdx.y; i < 32; i += 8) {
        int n = n0 + i, c = c0 + threadIdx.x;
        t[i][threadIdx.x] = (n < N && c < C) ? x[((size_t)b*N + n)*C + c] : 0.f;
    }
    __syncthreads();
    for (int i = threadIdx.y; i < 32; i += 8) {
        int c = c0 + i, n = n0 + threadIdx.x;
        if (c < C && n < N) H[((size_t)b*C + c)*N + n] = f2b(t[threadIdx.x][i]);
    }
}

// ---------------------------------------------------------------------------
// diffuse: X1[b] = H[b] @ A, X2[b] = H[b] @ A2   (shared H tile)
// block: 32x32 output tile, 256 threads, 2x2 micro-tile
// ---------------------------------------------------------------------------
__global__ __launch_bounds__(256)
void diffuse_kernel(const bf16* __restrict__ H, const float* __restrict__ A,
                    const float* __restrict__ A2,
                    bf16* __restrict__ X1, bf16* __restrict__ X2) {
    __shared__ float Ht[32][33], At[32][33], A2t[32][33];
    int b = blockIdx.z;
    int c0 = blockIdx.y*32, w0 = blockIdx.x*32;
    const bf16* Hb = H + (size_t)b*C*N;
    int tx = threadIdx.x & 15, ty = threadIdx.x >> 4;
    float acc1[2][2] = {}, acc2[2][2] = {};
    for (int k0 = 0; k0 < N; k0 += 32) {
        #pragma unroll
        for (int l = 0; l < 4; ++l) {
            int idx = threadIdx.x + l*256;
            int r = idx >> 5, col = idx & 31;
            int c = c0 + r, k = k0 + col;
            Ht[r][col] = (c < C && k < N) ? b2f(Hb[c*N + k]) : 0.f;
            int v = k0 + r, w = w0 + col;
            float a = 0.f, a2v = 0.f;
            if (v < N && w < N) { a = A[v*N + w]; a2v = A2[v*N + w]; }
            At[r][col] = a; A2t[r][col] = a2v;
        }
        __syncthreads();
        #pragma unroll
        for (int kk = 0; kk < 32; ++kk) {
            float h0 = Ht[ty][kk],    h1 = Ht[ty+16][kk];
            float a0 = At[kk][tx],    a1 = At[kk][tx+16];
            float b0 = A2t[kk][tx],   b1 = A2t[kk][tx+16];
            acc1[0][0] += h0*a0; acc1[0][1] += h0*a1;
            acc1[1][0] += h1*a0; acc1[1][1] += h1*a1;
            acc2[0][0] += h0*b0; acc2[0][1] += h0*b1;
            acc2[1][0] += h1*b0; acc2[1][1] += h1*b1;
        }
        __syncthreads();
    }
    bf16* X1b = X1 + (size_t)b*C*N;
    bf16* X2b = X2 + (size_t)b*C*N;
    #pragma unroll
    for (int i = 0; i < 2; ++i)
        #pragma unroll
        for (int j = 0; j < 2; ++j) {
            int c = c0 + ty + 16*i, w = w0 + tx + 16*j;
            if (c < C && w < N) {
                X1b[c*N + w] = f2b(acc1[i][j]);
                X2b[c*N + w] = f2b(acc2[i][j]);
            }
        }
}

// ---------------------------------------------------------------------------
// gconv: Hout[b] = BN( Wg @ [H;X1;X2][b] + bg )
// ---------------------------------------------------------------------------
__global__ __launch_bounds__(256)
void gconv_kernel(const bf16* __restrict__ H, const bf16* __restrict__ X1,
                  const bf16* __restrict__ X2,
                  const float* __restrict__ Wg, const float* __restrict__ bg,
                  const float* __restrict__ binv, const float* __restrict__ bshift,
                  bf16* __restrict__ Hout) {
    __shared__ float Wt[32][33], St[32][33];
    int b = blockIdx.z;
    int o0 = blockIdx.y*32, n0 = blockIdx.x*32;
    int tx = threadIdx.x & 15, ty = threadIdx.x >> 4;
    float acc[2][2] = {};
    const bf16* srcs[3] = { H + (size_t)b*C*N, X1 + (size_t)b*C*N, X2 + (size_t)b*C*N };
    for (int seg = 0; seg < 3; ++seg) {
        const bf16* S = srcs[seg];
        for (int k0 = 0; k0 < C; k0 += 32) {
            #pragma unroll
            for (int l = 0; l < 4; ++l) {
                int idx = threadIdx.x + l*256;
                int r = idx >> 5, col = idx & 31;
                int o = o0 + r, ck = k0 + col;
                Wt[r][col] = (o < C && ck < C) ? Wg[o*C3 + seg*C + ck] : 0.f;
                int c = k0 + r, n = n0 + col;
                St[r][col] = (c < C && n < N) ? b2f(S[c*N + n]) : 0.f;
            }
            __syncthreads();
            #pragma unroll
            for (int kk = 0; kk < 32; ++kk) {
                float w0v = Wt[ty][kk], w1v = Wt[ty+16][kk];
                float s0 = St[kk][tx],  s1 = St[kk][tx+16];
                acc[0][0] += w0v*s0; acc[0][1] += w0v*s1;
                acc[1][0] += w1v*s0; acc[1][1] += w1v*s1;
            }
            __syncthreads();
        }
    }
    bf16* Ob = Hout + (size_t)b*C*N;
    #pragma unroll
    for (int i = 0; i < 2; ++i) {
        int o = o0 + ty + 16*i;
        if (o >= C) continue;
        float iv = binv[o], sh = bshift[o], bias = bg[o];
        #pragma unroll
        for (int j = 0; j < 2; ++j) {
            int n = n0 + tx + 16*j;
            if (n >= N) continue;
            float g = acc[i][j] + bias;
            Ob[o*N + n] = f2b(g*iv + sh);
        }
    }
}

// ---------------------------------------------------------------------------
// final: out[b][n][o] = sum_c H[b][c][n] * Wm[o][c] + bm[o]
// o mapped to tx for coalesced transposed store
// ---------------------------------------------------------------------------
__global__ __launch_bounds__(256)
void final_kernel(const bf16* __restrict__ H, const float* __restrict__ Wm,
                  const float* __restrict__ bm, float* __restrict__ out) {
    __shared__ float Wt[32][33], Ht[32][33];
    int b = blockIdx.z;
    int o0 = blockIdx.y*32, n0 = blockIdx.x*32;
    int tx = threadIdx.x & 15, ty = threadIdx.x >> 4;
    float acc[2][2] = {};   // [io][jn]
    const bf16* Hb = H + (size_t)b*C*N;
    for (int k0 = 0; k0 < C; k0 += 32) {
        #pragma unroll
        for (int l = 0; l < 4; ++l) {
            int idx = threadIdx.x + l*256;
            int r = idx >> 5, col = idx & 31;
            int o = o0 + r, c = k0 + col;
            Wt[r][col] = (o < CO && c < C) ? Wm[o*C + c] : 0.f;
            int c2 = k0 + r, n = n0 + col;
            Ht[r][col] = (c2 < C && n < N) ? b2f(Hb[c2*N + n]) : 0.f;
        }
        __syncthreads();
        #pragma unroll
        for (int kk = 0; kk < 32; ++kk) {
            float w0v = Wt[tx][kk], w1v = Wt[tx+16][kk];
            float h0 = Ht[kk][ty],  h1 = Ht[kk][ty+16];
            acc[0][0] += w0v*h0; acc[0][1] += w0v*h1;
            acc[1][0] += w1v*h0; acc[1][1] += w1v*h1;
        }
        __syncthreads();
    }
    #pragma unroll
    for (int io = 0; io < 2; ++io) {
        int o = o0 + tx + 16*io;          // always < CO (512 % 32 == 0)
        float bias = bm[o];
        #pragma unroll
        for (int jn = 0; jn < 2; ++jn) {
            int n = n0 + ty + 16*jn;
            if (n >= N) continue;
            out[((size_t)b*N + n)*CO + o] = acc[io][jn] + bias;
        }
    }
}

static inline size_t align_up(size_t v, size_t a) { return (v + a - 1) & ~(a - 1); }

extern "C" void kernel_launch(void* const* d_in, const int* in_sizes, int n_in,
                              void* d_out, int out_size, void* d_ws, size_t ws_size,
                              hipStream_t stream) {
    const float* x     = (const float*)d_in[0];
    const float* nv1   = (const float*)d_in[1];
    const float* nv2   = (const float*)d_in[2];
    const float* Wg    = (const float*)d_in[3];
    const float* bg    = (const float*)d_in[4];
    const float* gamma = (const float*)d_in[5];
    const float* beta  = (const float*)d_in[6];
    const float* rmean = (const float*)d_in[7];
    const float* rvar  = (const float*)d_in[8];
    const float* Wm    = (const float*)d_in[9];
    const float* bm    = (const float*)d_in[10];
    float* out = (float*)d_out;

    char* ws = (char*)d_ws;
    const size_t bigN = (size_t)B*C*N*sizeof(bf16);
    float* A      = (float*)ws; ws += align_up((size_t)N*N*sizeof(float), 512);
    float* A2     = (float*)ws; ws += align_up((size_t)N*N*sizeof(float), 512);
    float* binv   = (float*)ws; ws += align_up((size_t)NLAYERS*C*sizeof(float), 512);
    float* bshift = (float*)ws; ws += align_up((size_t)NLAYERS*C*sizeof(float), 512);
    bf16* H0 = (bf16*)ws; ws += align_up(bigN, 512);
    bf16* H1 = (bf16*)ws; ws += align_up(bigN, 512);
    bf16* X1 = (bf16*)ws; ws += align_up(bigN, 512);
    bf16* X2 = (bf16*)ws; ws += align_up(bigN, 512);

    adp_kernel<<<N, 256, 0, stream>>>(nv1, nv2, A);
    a2_kernel<<<dim3(13, 13), dim3(16, 16), 0, stream>>>(A, A2);
    bn_kernel<<<2, 256, 0, stream>>>(gamma, beta, rmean, rvar, binv, bshift);
    transpose_kernel<<<dim3(7, 7, B), dim3(32, 8), 0, stream>>>(x, H0);

    // layer 0
    diffuse_kernel<<<dim3(7, 7, B), 256, 0, stream>>>(H0, A, A2, X1, X2);
    gconv_kernel<<<dim3(7, 7, B), 256, 0, stream>>>(H0, X1, X2,
        Wg + 0*(size_t)C*C3, bg + 0*C, binv + 0*C, bshift + 0*C, H1);

    // layer 1
    diffuse_kernel<<<dim3(7, 7, B), 256, 0, stream>>>(H1, A, A2, X1, X2);
    gconv_kernel<<<dim3(7, 7, B), 256, 0, stream>>>(H1, X1, X2,
        Wg + 1*(size_t)C*C3, bg + 1*C, binv + 1*C, bshift + 1*C, H0);

    // final conv
    final_kernel<<<dim3(7, 16, B), 256, 0, stream>>>(H0, Wm, bm, out);
}

// Round 2
// 564.214 us; speedup vs baseline: 8.1251x; 8.1251x over previous
//
#include <hip/hip_runtime.h>
#include <hip/hip_bf16.h>

#define B 512
#define N 207
#define C 207
#define CO 512
#define NLAYERS 2
#define EPS 1e-5f

#define STRIDE 224      // padded inner dim (elements)
#define ROWS 208        // padded row count for H-class buffers
#define KSTEPS 7        // 224/32

typedef unsigned short ushort;
typedef short s8v __attribute__((ext_vector_type(8)));
typedef float f4 __attribute__((ext_vector_type(4)));

__device__ __forceinline__ ushort f2bu(float f) {
    union { float f; unsigned int u; } v; v.f = f;
    unsigned int r = (v.u + 0x7FFF + ((v.u >> 16) & 1)) >> 16;
    return (ushort)r;
}
__device__ __forceinline__ float bu2f(ushort u) {
    union { unsigned int u; float f; } v; v.u = ((unsigned int)u) << 16;
    return v.f;
}

// ---------------------------------------------------------------------------
// P1[w][v] = softmax_j(relu(nv1[w,:]@nv2[:,j]))[v]  (row-major (w,v), bf16,
// padded 224x224 with zeros). One block per row w (224 blocks).
// ---------------------------------------------------------------------------
__global__ void adp_kernel(const float* __restrict__ nv1, const float* __restrict__ nv2,
                           ushort* __restrict__ P1) {
    int w = blockIdx.x, j = threadIdx.x;
    __shared__ float red[256];
    if (w >= 207) {                      // zero pad rows
        if (j < STRIDE) P1[w*STRIDE + j] = 0;
        return;
    }
    float val = 0.f;
    if (j < 207) {
        float acc = 0.f;
        #pragma unroll
        for (int k = 0; k < 10; ++k) acc += nv1[w*10 + k] * nv2[k*207 + j];
        val = fmaxf(acc, 0.f);
    }
    red[j] = (j < 207) ? val : -1e30f;
    __syncthreads();
    for (int off = 128; off > 0; off >>= 1) {
        if (j < off) red[j] = fmaxf(red[j], red[j+off]);
        __syncthreads();
    }
    float m = red[0];
    __syncthreads();
    float e = (j < 207) ? expf(val - m) : 0.f;
    red[j] = e;
    __syncthreads();
    for (int off = 128; off > 0; off >>= 1) {
        if (j < off) red[j] += red[j+off];
        __syncthreads();
    }
    float inv = 1.f / red[0];
    if (j < STRIDE) P1[w*STRIDE + j] = f2bu(e * inv);
}

// P2 = P1 @ P1  (row-major (w,v)); pads come out zero automatically
__global__ void p2_kernel(const ushort* __restrict__ P1, ushort* __restrict__ P2) {
    int v = blockIdx.x*16 + threadIdx.x;
    int w = blockIdx.y*16 + threadIdx.y;
    if (w < STRIDE && v < STRIDE) {
        float acc = 0.f;
        for (int u = 0; u < 207; ++u) acc += bu2f(P1[w*STRIDE + u]) * bu2f(P1[u*STRIDE + v]);
        P2[w*STRIDE + v] = f2bu(acc);
    }
}

// BN fold, padded to 208: binv[o>=207]=0, bfold[o>=207]=0
__global__ void bn_kernel(const float* __restrict__ gamma, const float* __restrict__ beta,
                          const float* __restrict__ rmean, const float* __restrict__ rvar,
                          const float* __restrict__ bg,
                          float* __restrict__ binv, float* __restrict__ bfold) {
    int i = blockIdx.x*256 + threadIdx.x;
    if (i >= NLAYERS*ROWS) return;
    int l = i / ROWS, o = i % ROWS;
    float iv = 0.f, bf = 0.f;
    if (o < 207) {
        float g = gamma[l*207 + o];
        iv = g * rsqrtf(rvar[l*207 + o] + EPS);
        bf = bg[l*207 + o]*iv + beta[l*207 + o] - rmean[l*207 + o]*iv;
    }
    binv[i] = iv; bfold[i] = bf;
}

// Wg (L,207,621) f32 -> Wgp (L,3,208,224) bf16 zero-padded
__global__ void wg_prep(const float* __restrict__ Wg, ushort* __restrict__ Wgp) {
    int idx = blockIdx.x*256 + threadIdx.x;
    if (idx >= NLAYERS*3*ROWS*STRIDE) return;
    int k = idx % STRIDE;
    int o = (idx / STRIDE) % ROWS;
    int seg = (idx / (STRIDE*ROWS)) % 3;
    int l = idx / (STRIDE*ROWS*3);
    float v = (o < 207 && k < 207) ? Wg[((size_t)(l*207 + o))*621 + seg*207 + k] : 0.f;
    Wgp[idx] = f2bu(v);
}

// Wm (512,207) f32 -> Wmp (512,224) bf16 zero-padded
__global__ void wm_prep(const float* __restrict__ Wm, ushort* __restrict__ Wmp) {
    int idx = blockIdx.x*256 + threadIdx.x;
    if (idx >= CO*STRIDE) return;
    int k = idx % STRIDE, o = idx / STRIDE;
    Wmp[idx] = f2bu(k < 207 ? Wm[o*207 + k] : 0.f);
}

// x (B,207,207) f32 -> Hcv (B,208,224) bf16 : Hcv[c][n] = x[n][c]
__global__ void h0cv_kernel(const float* __restrict__ x, ushort* __restrict__ Hcv) {
    __shared__ float t[32][33];
    int b = blockIdx.z;
    int n0 = blockIdx.x*32, c0 = blockIdx.y*32;
    int tx = threadIdx.x, ty = threadIdx.y;
    for (int i = ty; i < 32; i += 8) {
        int n = n0 + i, c = c0 + tx;
        t[i][tx] = (n < 207 && c < 207) ? x[((size_t)b*207 + n)*207 + c] : 0.f;
    }
    __syncthreads();
    size_t base = (size_t)b*ROWS*STRIDE;
    for (int i = ty; i < 32; i += 8) {
        int c = c0 + i, n = n0 + tx;
        if (c < ROWS && n < STRIDE) Hcv[base + (size_t)c*STRIDE + n] = f2bu(t[tx][i]);
    }
}

// x (B,207,207) f32 -> Hnc (B,208,224) bf16 : Hnc[n][c] = x[n][c]
__global__ void h0nc_kernel(const float* __restrict__ x, ushort* __restrict__ Hnc) {
    size_t idx = (size_t)blockIdx.x*256 + threadIdx.x;
    if (idx >= (size_t)B*ROWS*STRIDE) return;
    int c = idx % STRIDE;
    int n = (idx / STRIDE) % ROWS;
    size_t b = idx / (STRIDE*ROWS);
    ushort v = 0;
    if (n < 207 && c < 207) v = f2bu(x[(b*207 + n)*207 + c]);
    Hnc[idx] = v;
}

// bf16 transpose: out[n][c] = in[c][n], per batch (208x224 padded both sides)
__global__ void tr_kernel(const ushort* __restrict__ in, ushort* __restrict__ out) {
    __shared__ ushort t[32][33];
    int b = blockIdx.z;
    size_t base = (size_t)b*ROWS*STRIDE;
    int n0 = blockIdx.x*32, c0 = blockIdx.y*32;
    int tx = threadIdx.x, ty = threadIdx.y;
    for (int i = ty; i < 32; i += 8) {
        int c = c0 + i, n = n0 + tx;
        t[i][tx] = (c < ROWS && n < STRIDE) ? in[base + (size_t)c*STRIDE + n] : 0;
    }
    __syncthreads();
    for (int i = ty; i < 32; i += 8) {
        int n = n0 + i, c = c0 + tx;
        if (n < ROWS && c < STRIDE) out[base + (size_t)n*STRIDE + c] = t[tx][i];
    }
}

// ---------------------------------------------------------------------------
// shared staging helper: stage 128x32 bf16 tile (row-major, k contiguous)
// rows clamped to rmax (clamped rows must be zero rows in src)
// ---------------------------------------------------------------------------
__device__ __forceinline__ void stage_tile(ushort* __restrict__ tile,
                                           const ushort* __restrict__ src,
                                           int rbase, int rmax, int kbase, int tid) {
    #pragma unroll
    for (int i = 0; i < 2; ++i) {
        int rt = i*64 + (tid >> 2);
        int gr = rbase + rt; gr = (gr > rmax) ? rmax : gr;
        s8v v = *(const s8v*)(src + (size_t)gr*STRIDE + kbase + (tid & 3)*8);
        *(s8v*)(tile + rt*32 + (tid & 3)*8) = v;
    }
}

// ---------------------------------------------------------------------------
// diffuse: X1[w][c] = sum_v P1[w][v]*Hcv[c][v]; X2 same with P2. Shared B tile.
// block tile 128x128 (m=w, n_=c), 4 waves 2x2, wave tile 64x64
// ---------------------------------------------------------------------------
__global__ __launch_bounds__(256, 2)
void diffuse_kernel(const ushort* __restrict__ Hcv, const ushort* __restrict__ P1,
                    const ushort* __restrict__ P2,
                    ushort* __restrict__ X1, ushort* __restrict__ X2) {
    __shared__ __align__(16) ushort A1t[128*32], A2t[128*32], Bt[128*32];
    int b = blockIdx.z;
    int w0 = blockIdx.x*128, c0 = blockIdx.y*128;
    const ushort* Hb = Hcv + (size_t)b*ROWS*STRIDE;
    int tid = threadIdx.x, lane = tid & 63, wid = tid >> 6;
    int wm = wid >> 1, wn = wid & 1;
    int frow = lane & 15, fko = (lane >> 4)*8;

    f4 acc1[4][4], acc2[4][4];
    #pragma unroll
    for (int i = 0; i < 4; ++i)
        #pragma unroll
        for (int j = 0; j < 4; ++j) { acc1[i][j] = (f4)0.f; acc2[i][j] = (f4)0.f; }

    for (int ks = 0; ks < KSTEPS; ++ks) {
        int k0 = ks*32;
        stage_tile(A1t, P1, w0, 223, k0, tid);
        stage_tile(A2t, P2, w0, 223, k0, tid);
        stage_tile(Bt,  Hb, c0, 207, k0, tid);
        __syncthreads();
        s8v a1[4], a2[4], bf[4];
        #pragma unroll
        for (int f = 0; f < 4; ++f) {
            a1[f] = *(const s8v*)&A1t[(wm*64 + f*16 + frow)*32 + fko];
            a2[f] = *(const s8v*)&A2t[(wm*64 + f*16 + frow)*32 + fko];
            bf[f] = *(const s8v*)&Bt [(wn*64 + f*16 + frow)*32 + fko];
        }
        #pragma unroll
        for (int fm = 0; fm < 4; ++fm)
            #pragma unroll
            for (int fn = 0; fn < 4; ++fn) {
                acc1[fm][fn] = __builtin_amdgcn_mfma_f32_16x16x32_bf16(a1[fm], bf[fn], acc1[fm][fn], 0, 0, 0);
                acc2[fm][fn] = __builtin_amdgcn_mfma_f32_16x16x32_bf16(a2[fm], bf[fn], acc2[fm][fn], 0, 0, 0);
            }
        __syncthreads();
    }

    ushort* X1b = X1 + (size_t)b*ROWS*STRIDE;
    ushort* X2b = X2 + (size_t)b*ROWS*STRIDE;
    int g4 = (lane >> 4)*4;
    #pragma unroll
    for (int fm = 0; fm < 4; ++fm)
        #pragma unroll
        for (int fn = 0; fn < 4; ++fn) {
            int ocol = c0 + wn*64 + fn*16 + (lane & 15);
            if (ocol >= STRIDE) continue;
            #pragma unroll
            for (int r = 0; r < 4; ++r) {
                int orow = w0 + wm*64 + fm*16 + g4 + r;
                if (orow < ROWS) {
                    X1b[(size_t)orow*STRIDE + ocol] = f2bu(acc1[fm][fn][r]);
                    X2b[(size_t)orow*STRIDE + ocol] = f2bu(acc2[fm][fn][r]);
                }
            }
        }
}

// ---------------------------------------------------------------------------
// gconv: Hout[o][n] = BN( sum_c' Wg[o][c'] * cat[c'][n] + bg )
// A = Wgp (o,k) , B = {Hnc,X1,X2} (n,k), out (o,n)-major (=Hcv layout)
// ---------------------------------------------------------------------------
__global__ __launch_bounds__(256, 2)
void gconv_kernel(const ushort* __restrict__ Hnc, const ushort* __restrict__ X1,
                  const ushort* __restrict__ X2, const ushort* __restrict__ Wgp,
                  const float* __restrict__ binv, const float* __restrict__ bfold,
                  int layer, ushort* __restrict__ Hout) {
    __shared__ __align__(16) ushort At[128*32], Bt[128*32];
    int b = blockIdx.z;
    int o0 = blockIdx.x*128, n0 = blockIdx.y*128;
    size_t boff = (size_t)b*ROWS*STRIDE;
    const ushort* srcs[3] = { Hnc + boff, X1 + boff, X2 + boff };
    int tid = threadIdx.x, lane = tid & 63, wid = tid >> 6;
    int wm = wid >> 1, wn = wid & 1;
    int frow = lane & 15, fko = (lane >> 4)*8;

    f4 acc[4][4];
    #pragma unroll
    for (int i = 0; i < 4; ++i)
        #pragma unroll
        for (int j = 0; j < 4; ++j) acc[i][j] = (f4)0.f;

    for (int ks = 0; ks < 3*KSTEPS; ++ks) {
        int seg = ks / KSTEPS;
        int k0 = (ks % KSTEPS)*32;
        const ushort* As = Wgp + (size_t)(layer*3 + seg)*ROWS*STRIDE;
        stage_tile(At, As, o0, 207, k0, tid);
        stage_tile(Bt, srcs[seg], n0, 207, k0, tid);
        __syncthreads();
        s8v a[4], bf[4];
        #pragma unroll
        for (int f = 0; f < 4; ++f) {
            a[f]  = *(const s8v*)&At[(wm*64 + f*16 + frow)*32 + fko];
            bf[f] = *(const s8v*)&Bt[(wn*64 + f*16 + frow)*32 + fko];
        }
        #pragma unroll
        for (int fm = 0; fm < 4; ++fm)
            #pragma unroll
            for (int fn = 0; fn < 4; ++fn)
                acc[fm][fn] = __builtin_amdgcn_mfma_f32_16x16x32_bf16(a[fm], bf[fn], acc[fm][fn], 0, 0, 0);
        __syncthreads();
    }

    ushort* Ob = Hout + boff;
    int g4 = (lane >> 4)*4;
    #pragma unroll
    for (int fm = 0; fm < 4; ++fm) {
        #pragma unroll
        for (int fn = 0; fn < 4; ++fn) {
            int ocol = n0 + wn*64 + fn*16 + (lane & 15);
            if (ocol >= STRIDE) continue;
            #pragma unroll
            for (int r = 0; r < 4; ++r) {
                int orow = o0 + wm*64 + fm*16 + g4 + r;
                if (orow < ROWS) {
                    float iv = binv[layer*ROWS + orow], bfv = bfold[layer*ROWS + orow];
                    float h = acc[fm][fn][r]*iv + bfv;
                    Ob[(size_t)orow*STRIDE + ocol] = (ocol < 207) ? f2bu(h) : (ushort)0;
                }
            }
        }
    }
}

// ---------------------------------------------------------------------------
// final: out[b][n][o] = sum_c Hnc[n][c]*Wm[o][c] + bm[o]
// A = Hnc (n,k), B = Wmp (o,k), D (n,o) stored directly to output (coalesced)
// ---------------------------------------------------------------------------
__global__ __launch_bounds__(256, 2)
void final_kernel(const ushort* __restrict__ Hnc, const ushort* __restrict__ Wmp,
                  const float* __restrict__ bm, float* __restrict__ out) {
    __shared__ __align__(16) ushort At[128*32], Bt[128*32];
    int b = blockIdx.z;
    int n0 = blockIdx.x*128, o0 = blockIdx.y*128;
    const ushort* Hb = Hnc + (size_t)b*ROWS*STRIDE;
    int tid = threadIdx.x, lane = tid & 63, wid = tid >> 6;
    int wm = wid >> 1, wn = wid & 1;
    int frow = lane & 15, fko = (lane >> 4)*8;

    f4 acc[4][4];
    #pragma unroll
    for (int i = 0; i < 4; ++i)
        #pragma unroll
        for (int j = 0; j < 4; ++j) acc[i][j] = (f4)0.f;

    for (int ks = 0; ks < KSTEPS; ++ks) {
        int k0 = ks*32;
        stage_tile(At, Hb,  n0, 207, k0, tid);
        stage_tile(Bt, Wmp, o0, 511, k0, tid);
        __syncthreads();
        s8v a[4], bf[4];
        #pragma unroll
        for (int f = 0; f < 4; ++f) {
            a[f]  = *(const s8v*)&At[(wm*64 + f*16 + frow)*32 + fko];
            bf[f] = *(const s8v*)&Bt[(wn*64 + f*16 + frow)*32 + fko];
        }
        #pragma unroll
        for (int fm = 0; fm < 4; ++fm)
            #pragma unroll
            for (int fn = 0; fn < 4; ++fn)
                acc[fm][fn] = __builtin_amdgcn_mfma_f32_16x16x32_bf16(a[fm], bf[fn], acc[fm][fn], 0, 0, 0);
        __syncthreads();
    }

    int g4 = (lane >> 4)*4;
    #pragma unroll
    for (int fm = 0; fm < 4; ++fm)
        #pragma unroll
        for (int fn = 0; fn < 4; ++fn) {
            int o = o0 + wn*64 + fn*16 + (lane & 15);   // < 512 always
            float bias = bm[o];
            #pragma unroll
            for (int r = 0; r < 4; ++r) {
                int n = n0 + wm*64 + fm*16 + g4 + r;
                if (n < 207) out[((size_t)b*207 + n)*CO + o] = acc[fm][fn][r] + bias;
            }
        }
}

static inline size_t align_up(size_t v, size_t a) { return (v + a - 1) & ~(a - 1); }

extern "C" void kernel_launch(void* const* d_in, const int* in_sizes, int n_in,
                              void* d_out, int out_size, void* d_ws, size_t ws_size,
                              hipStream_t stream) {
    const float* x     = (const float*)d_in[0];
    const float* nv1   = (const float*)d_in[1];
    const float* nv2   = (const float*)d_in[2];
    const float* Wg    = (const float*)d_in[3];
    const float* bg    = (const float*)d_in[4];
    const float* gamma = (const float*)d_in[5];
    const float* beta  = (const float*)d_in[6];
    const float* rmean = (const float*)d_in[7];
    const float* rvar  = (const float*)d_in[8];
    const float* Wm    = (const float*)d_in[9];
    const float* bm    = (const float*)d_in[10];
    float* out = (float*)d_out;

    char* ws = (char*)d_ws;
    const size_t bufN = (size_t)B*ROWS*STRIDE*sizeof(ushort);   // 47.7 MB
    ushort* P1   = (ushort*)ws; ws += align_up((size_t)STRIDE*STRIDE*2, 512);
    ushort* P2   = (ushort*)ws; ws += align_up((size_t)STRIDE*STRIDE*2, 512);
    float* binv  = (float*)ws;  ws += align_up((size_t)NLAYERS*ROWS*4, 512);
    float* bfold = (float*)ws;  ws += align_up((size_t)NLAYERS*ROWS*4, 512);
    ushort* Wgp  = (ushort*)ws; ws += align_up((size_t)NLAYERS*3*ROWS*STRIDE*2, 512);
    ushort* Wmp  = (ushort*)ws; ws += align_up((size_t)CO*STRIDE*2, 512);
    ushort* buf0 = (ushort*)ws; ws += align_up(bufN, 512);   // Hcv-class
    ushort* buf1 = (ushort*)ws; ws += align_up(bufN, 512);   // Hnc-class
    ushort* buf2 = (ushort*)ws; ws += align_up(bufN, 512);   // X1
    ushort* buf3 = (ushort*)ws; ws += align_up(bufN, 512);   // X2

    // --- prep ---
    adp_kernel<<<STRIDE, 256, 0, stream>>>(nv1, nv2, P1);
    p2_kernel<<<dim3(14, 14), dim3(16, 16), 0, stream>>>(P1, P2);
    bn_kernel<<<(NLAYERS*ROWS + 255)/256, 256, 0, stream>>>(gamma, beta, rmean, rvar, bg, binv, bfold);
    wg_prep<<<(NLAYERS*3*ROWS*STRIDE + 255)/256, 256, 0, stream>>>(Wg, Wgp);
    wm_prep<<<(CO*STRIDE + 255)/256, 256, 0, stream>>>(Wm, Wmp);
    h0cv_kernel<<<dim3(7, 7, B), dim3(32, 8), 0, stream>>>(x, buf0);
    h0nc_kernel<<<(int)(((size_t)B*ROWS*STRIDE + 255)/256), 256, 0, stream>>>(x, buf1);

    // --- layer 0 ---
    diffuse_kernel<<<dim3(2, 2, B), 256, 0, stream>>>(buf0, P1, P2, buf2, buf3);
    gconv_kernel<<<dim3(2, 2, B), 256, 0, stream>>>(buf1, buf2, buf3, Wgp, binv, bfold, 0, buf0); // H1cv -> buf0
    tr_kernel<<<dim3(7, 7, B), dim3(32, 8), 0, stream>>>(buf0, buf1);                             // H1nc -> buf1

    // --- layer 1 ---
    diffuse_kernel<<<dim3(2, 2, B), 256, 0, stream>>>(buf0, P1, P2, buf2, buf3);
    gconv_kernel<<<dim3(2, 2, B), 256, 0, stream>>>(buf1, buf2, buf3, Wgp, binv, bfold, 1, buf0); // H2cv -> buf0
    tr_kernel<<<dim3(7, 7, B), dim3(32, 8), 0, stream>>>(buf0, buf1);                             // H2nc -> buf1

    // --- final ---
    final_kernel<<<dim3(2, 4, B), 256, 0, stream>>>(buf1, Wmp, bm, out);
}

// Round 3
// 528.398 us; speedup vs baseline: 8.6758x; 1.0678x over previous
//
#include <hip/hip_runtime.h>
#include <hip/hip_bf16.h>

#define B 512
#define N 207
#define C 207
#define CO 512
#define NLAYERS 2
#define EPS 1e-5f

#define STRIDE 224      // padded inner dim (elements)
#define ROWS 208        // padded row count for H-class buffers
#define KSTEPS 7        // 224/32

typedef unsigned short ushort;
typedef short s8v __attribute__((ext_vector_type(8)));
typedef float f4 __attribute__((ext_vector_type(4)));

__device__ __forceinline__ ushort f2bu(float f) {
    union { float f; unsigned int u; } v; v.f = f;
    unsigned int r = (v.u + 0x7FFF + ((v.u >> 16) & 1)) >> 16;
    return (ushort)r;
}
__device__ __forceinline__ float bu2f(ushort u) {
    union { unsigned int u; float f; } v; v.u = ((unsigned int)u) << 16;
    return v.f;
}

// ---------------------------------------------------------------------------
// P1[w][v] = softmax_j(relu(nv1[w,:]@nv2[:,j]))[v]  (row-major (w,v), bf16,
// padded 224x224 with zeros). One block per row w (224 blocks).
// ---------------------------------------------------------------------------
__global__ void adp_kernel(const float* __restrict__ nv1, const float* __restrict__ nv2,
                           ushort* __restrict__ P1) {
    int w = blockIdx.x, j = threadIdx.x;
    __shared__ float red[256];
    if (w >= 207) {                      // zero pad rows
        if (j < STRIDE) P1[w*STRIDE + j] = 0;
        return;
    }
    float val = 0.f;
    if (j < 207) {
        float acc = 0.f;
        #pragma unroll
        for (int k = 0; k < 10; ++k) acc += nv1[w*10 + k] * nv2[k*207 + j];
        val = fmaxf(acc, 0.f);
    }
    red[j] = (j < 207) ? val : -1e30f;
    __syncthreads();
    for (int off = 128; off > 0; off >>= 1) {
        if (j < off) red[j] = fmaxf(red[j], red[j+off]);
        __syncthreads();
    }
    float m = red[0];
    __syncthreads();
    float e = (j < 207) ? expf(val - m) : 0.f;
    red[j] = e;
    __syncthreads();
    for (int off = 128; off > 0; off >>= 1) {
        if (j < off) red[j] += red[j+off];
        __syncthreads();
    }
    float inv = 1.f / red[0];
    if (j < STRIDE) P1[w*STRIDE + j] = f2bu(e * inv);
}

// P2 = P1 @ P1  (row-major (w,v)); pads come out zero automatically
__global__ void p2_kernel(const ushort* __restrict__ P1, ushort* __restrict__ P2) {
    int v = blockIdx.x*16 + threadIdx.x;
    int w = blockIdx.y*16 + threadIdx.y;
    if (w < STRIDE && v < STRIDE) {
        float acc = 0.f;
        for (int u = 0; u < 207; ++u) acc += bu2f(P1[w*STRIDE + u]) * bu2f(P1[u*STRIDE + v]);
        P2[w*STRIDE + v] = f2bu(acc);
    }
}

// BN fold, padded to 208: binv[o>=207]=0, bfold[o>=207]=0
__global__ void bn_kernel(const float* __restrict__ gamma, const float* __restrict__ beta,
                          const float* __restrict__ rmean, const float* __restrict__ rvar,
                          const float* __restrict__ bg,
                          float* __restrict__ binv, float* __restrict__ bfold) {
    int i = blockIdx.x*256 + threadIdx.x;
    if (i >= NLAYERS*ROWS) return;
    int l = i / ROWS, o = i % ROWS;
    float iv = 0.f, bf = 0.f;
    if (o < 207) {
        float g = gamma[l*207 + o];
        iv = g * rsqrtf(rvar[l*207 + o] + EPS);
        bf = bg[l*207 + o]*iv + beta[l*207 + o] - rmean[l*207 + o]*iv;
    }
    binv[i] = iv; bfold[i] = bf;
}

// Wg (L,207,621) f32 -> Wgp (L,3,208,224) bf16 zero-padded
__global__ void wg_prep(const float* __restrict__ Wg, ushort* __restrict__ Wgp) {
    int idx = blockIdx.x*256 + threadIdx.x;
    if (idx >= NLAYERS*3*ROWS*STRIDE) return;
    int k = idx % STRIDE;
    int o = (idx / STRIDE) % ROWS;
    int seg = (idx / (STRIDE*ROWS)) % 3;
    int l = idx / (STRIDE*ROWS*3);
    float v = (o < 207 && k < 207) ? Wg[((size_t)(l*207 + o))*621 + seg*207 + k] : 0.f;
    Wgp[idx] = f2bu(v);
}

// Wm (512,207) f32 -> Wmp (512,224) bf16 zero-padded
__global__ void wm_prep(const float* __restrict__ Wm, ushort* __restrict__ Wmp) {
    int idx = blockIdx.x*256 + threadIdx.x;
    if (idx >= CO*STRIDE) return;
    int k = idx % STRIDE, o = idx / STRIDE;
    Wmp[idx] = f2bu(k < 207 ? Wm[o*207 + k] : 0.f);
}

// x (B,207,207) f32 -> Hcv (B,208,224) [c][n]  AND  Hnc (B,208,224) [n][c]
// single read of x, dual-layout write
__global__ void h0_kernel(const float* __restrict__ x, ushort* __restrict__ Hcv,
                          ushort* __restrict__ Hnc) {
    __shared__ float t[32][33];
    int b = blockIdx.z;
    int n0 = blockIdx.x*32, c0 = blockIdx.y*32;
    int tx = threadIdx.x, ty = threadIdx.y;
    for (int i = ty; i < 32; i += 8) {
        int n = n0 + i, c = c0 + tx;
        t[i][tx] = (n < 207 && c < 207) ? x[((size_t)b*207 + n)*207 + c] : 0.f;
    }
    __syncthreads();
    size_t base = (size_t)b*ROWS*STRIDE;
    for (int i = ty; i < 32; i += 8) {
        int n = n0 + i, c = c0 + tx;
        if (n < ROWS && c < STRIDE) Hnc[base + (size_t)n*STRIDE + c] = f2bu(t[i][tx]);
    }
    for (int i = ty; i < 32; i += 8) {
        int c = c0 + i, n = n0 + tx;
        if (c < ROWS && n < STRIDE) Hcv[base + (size_t)c*STRIDE + n] = f2bu(t[tx][i]);
    }
}

// bf16 transpose: out[n][c] = in[c][n], per batch (208x224 padded both sides)
__global__ void tr_kernel(const ushort* __restrict__ in, ushort* __restrict__ out) {
    __shared__ ushort t[32][33];
    int b = blockIdx.z;
    size_t base = (size_t)b*ROWS*STRIDE;
    int n0 = blockIdx.x*32, c0 = blockIdx.y*32;
    int tx = threadIdx.x, ty = threadIdx.y;
    for (int i = ty; i < 32; i += 8) {
        int c = c0 + i, n = n0 + tx;
        t[i][tx] = (c < ROWS && n < STRIDE) ? in[base + (size_t)c*STRIDE + n] : 0;
    }
    __syncthreads();
    for (int i = ty; i < 32; i += 8) {
        int n = n0 + i, c = c0 + tx;
        if (n < ROWS && c < STRIDE) out[base + (size_t)n*STRIDE + c] = t[tx][i];
    }
}

// ---------------------------------------------------------------------------
// async staging: 128x32 bf16 tile via global_load_lds (16B/lane).
// LDS layout is linear in lane order: per wave, base + lane*16B.
// rows clamped to rmax (clamped rows must be zero rows in src).
// ---------------------------------------------------------------------------
__device__ __forceinline__ void stage_async(ushort* __restrict__ tile,
                                            const ushort* __restrict__ src,
                                            int rbase, int rmax, int kbase, int tid) {
    int lane = tid & 63, wave = tid >> 6;
    #pragma unroll
    for (int i = 0; i < 2; ++i) {
        int r = rbase + i*64 + wave*16 + (lane >> 2);
        r = (r > rmax) ? rmax : r;
        const ushort* g = src + (size_t)r*STRIDE + kbase + (lane & 3)*8;
        ushort* l = tile + i*2048 + wave*512;          // wave-uniform base
        __builtin_amdgcn_global_load_lds(
            (const __attribute__((address_space(1))) void*)g,
            (__attribute__((address_space(3))) void*)l, 16, 0, 0);
    }
}

// ---------------------------------------------------------------------------
// diffuse: X1[w][c] = sum_v P1[w][v]*Hcv[c][v]; X2 same with P2. Shared B tile.
// block tile 128x128 (m=w, n_=c), 4 waves 2x2, wave tile 64x64
// ---------------------------------------------------------------------------
__global__ __launch_bounds__(256, 2)
void diffuse_kernel(const ushort* __restrict__ Hcv, const ushort* __restrict__ P1,
                    const ushort* __restrict__ P2,
                    ushort* __restrict__ X1, ushort* __restrict__ X2) {
    __shared__ __align__(16) ushort A1t[128*32], A2t[128*32], Bt[128*32];
    int b = blockIdx.z;
    int w0 = blockIdx.x*128, c0 = blockIdx.y*128;
    const ushort* Hb = Hcv + (size_t)b*ROWS*STRIDE;
    int tid = threadIdx.x, lane = tid & 63, wid = tid >> 6;
    int wm = wid >> 1, wn = wid & 1;
    int frow = lane & 15, fko = (lane >> 4)*8;

    f4 acc1[4][4], acc2[4][4];
    #pragma unroll
    for (int i = 0; i < 4; ++i)
        #pragma unroll
        for (int j = 0; j < 4; ++j) { acc1[i][j] = (f4)0.f; acc2[i][j] = (f4)0.f; }

    for (int ks = 0; ks < KSTEPS; ++ks) {
        int k0 = ks*32;
        stage_async(A1t, P1, w0, 223, k0, tid);
        stage_async(A2t, P2, w0, 223, k0, tid);
        stage_async(Bt,  Hb, c0, 207, k0, tid);
        __syncthreads();
        s8v a1[4], a2[4], bf[4];
        #pragma unroll
        for (int f = 0; f < 4; ++f) {
            a1[f] = *(const s8v*)&A1t[(wm*64 + f*16 + frow)*32 + fko];
            a2[f] = *(const s8v*)&A2t[(wm*64 + f*16 + frow)*32 + fko];
            bf[f] = *(const s8v*)&Bt [(wn*64 + f*16 + frow)*32 + fko];
        }
        #pragma unroll
        for (int fm = 0; fm < 4; ++fm)
            #pragma unroll
            for (int fn = 0; fn < 4; ++fn) {
                acc1[fm][fn] = __builtin_amdgcn_mfma_f32_16x16x32_bf16(a1[fm], bf[fn], acc1[fm][fn], 0, 0, 0);
                acc2[fm][fn] = __builtin_amdgcn_mfma_f32_16x16x32_bf16(a2[fm], bf[fn], acc2[fm][fn], 0, 0, 0);
            }
        __syncthreads();
    }

    ushort* X1b = X1 + (size_t)b*ROWS*STRIDE;
    ushort* X2b = X2 + (size_t)b*ROWS*STRIDE;
    int g4 = (lane >> 4)*4;
    #pragma unroll
    for (int fm = 0; fm < 4; ++fm)
        #pragma unroll
        for (int fn = 0; fn < 4; ++fn) {
            int ocol = c0 + wn*64 + fn*16 + (lane & 15);
            if (ocol >= STRIDE) continue;
            #pragma unroll
            for (int r = 0; r < 4; ++r) {
                int orow = w0 + wm*64 + fm*16 + g4 + r;
                if (orow < ROWS) {
                    X1b[(size_t)orow*STRIDE + ocol] = f2bu(acc1[fm][fn][r]);
                    X2b[(size_t)orow*STRIDE + ocol] = f2bu(acc2[fm][fn][r]);
                }
            }
        }
}

// ---------------------------------------------------------------------------
// gconv: Hout[o][n] = BN( sum_c' Wg[o][c'] * cat[c'][n] + bg )
// A = Wgp (o,k) , B = {Hnc,X1,X2} (n,k), out (o,n)-major (=Hcv layout)
// ---------------------------------------------------------------------------
__global__ __launch_bounds__(256, 2)
void gconv_kernel(const ushort* __restrict__ Hnc, const ushort* __restrict__ X1,
                  const ushort* __restrict__ X2, const ushort* __restrict__ Wgp,
                  const float* __restrict__ binv, const float* __restrict__ bfold,
                  int layer, ushort* __restrict__ Hout) {
    __shared__ __align__(16) ushort At[128*32], Bt[128*32];
    int b = blockIdx.z;
    int o0 = blockIdx.x*128, n0 = blockIdx.y*128;
    size_t boff = (size_t)b*ROWS*STRIDE;
    const ushort* srcs[3] = { Hnc + boff, X1 + boff, X2 + boff };
    int tid = threadIdx.x, lane = tid & 63, wid = tid >> 6;
    int wm = wid >> 1, wn = wid & 1;
    int frow = lane & 15, fko = (lane >> 4)*8;

    f4 acc[4][4];
    #pragma unroll
    for (int i = 0; i < 4; ++i)
        #pragma unroll
        for (int j = 0; j < 4; ++j) acc[i][j] = (f4)0.f;

    for (int ks = 0; ks < 3*KSTEPS; ++ks) {
        int seg = ks / KSTEPS;
        int k0 = (ks % KSTEPS)*32;
        const ushort* As = Wgp + (size_t)(layer*3 + seg)*ROWS*STRIDE;
        stage_async(At, As, o0, 207, k0, tid);
        stage_async(Bt, srcs[seg], n0, 207, k0, tid);
        __syncthreads();
        s8v a[4], bf[4];
        #pragma unroll
        for (int f = 0; f < 4; ++f) {
            a[f]  = *(const s8v*)&At[(wm*64 + f*16 + frow)*32 + fko];
            bf[f] = *(const s8v*)&Bt[(wn*64 + f*16 + frow)*32 + fko];
        }
        #pragma unroll
        for (int fm = 0; fm < 4; ++fm)
            #pragma unroll
            for (int fn = 0; fn < 4; ++fn)
                acc[fm][fn] = __builtin_amdgcn_mfma_f32_16x16x32_bf16(a[fm], bf[fn], acc[fm][fn], 0, 0, 0);
        __syncthreads();
    }

    ushort* Ob = Hout + boff;
    int g4 = (lane >> 4)*4;
    #pragma unroll
    for (int fm = 0; fm < 4; ++fm) {
        #pragma unroll
        for (int fn = 0; fn < 4; ++fn) {
            int ocol = n0 + wn*64 + fn*16 + (lane & 15);
            if (ocol >= STRIDE) continue;
            #pragma unroll
            for (int r = 0; r < 4; ++r) {
                int orow = o0 + wm*64 + fm*16 + g4 + r;
                if (orow < ROWS) {
                    float iv = binv[layer*ROWS + orow], bfv = bfold[layer*ROWS + orow];
                    float h = acc[fm][fn][r]*iv + bfv;
                    Ob[(size_t)orow*STRIDE + ocol] = (ocol < 207) ? f2bu(h) : (ushort)0;
                }
            }
        }
    }
}

// ---------------------------------------------------------------------------
// final: out[b][n][o] = sum_c Hnc[n][c]*Wm[o][c] + bm[o]
// A = Hnc (n,k), B = Wmp (o,k), D (n,o) stored directly to output (coalesced)
// ---------------------------------------------------------------------------
__global__ __launch_bounds__(256, 2)
void final_kernel(const ushort* __restrict__ Hnc, const ushort* __restrict__ Wmp,
                  const float* __restrict__ bm, float* __restrict__ out) {
    __shared__ __align__(16) ushort At[128*32], Bt[128*32];
    int b = blockIdx.z;
    int n0 = blockIdx.x*128, o0 = blockIdx.y*128;
    const ushort* Hb = Hnc + (size_t)b*ROWS*STRIDE;
    int tid = threadIdx.x, lane = tid & 63, wid = tid >> 6;
    int wm = wid >> 1, wn = wid & 1;
    int frow = lane & 15, fko = (lane >> 4)*8;

    f4 acc[4][4];
    #pragma unroll
    for (int i = 0; i < 4; ++i)
        #pragma unroll
        for (int j = 0; j < 4; ++j) acc[i][j] = (f4)0.f;

    for (int ks = 0; ks < KSTEPS; ++ks) {
        int k0 = ks*32;
        stage_async(At, Hb,  n0, 207, k0, tid);
        stage_async(Bt, Wmp, o0, 511, k0, tid);
        __syncthreads();
        s8v a[4], bf[4];
        #pragma unroll
        for (int f = 0; f < 4; ++f) {
            a[f]  = *(const s8v*)&At[(wm*64 + f*16 + frow)*32 + fko];
            bf[f] = *(const s8v*)&Bt[(wn*64 + f*16 + frow)*32 + fko];
        }
        #pragma unroll
        for (int fm = 0; fm < 4; ++fm)
            #pragma unroll
            for (int fn = 0; fn < 4; ++fn)
                acc[fm][fn] = __builtin_amdgcn_mfma_f32_16x16x32_bf16(a[fm], bf[fn], acc[fm][fn], 0, 0, 0);
        __syncthreads();
    }

    int g4 = (lane >> 4)*4;
    #pragma unroll
    for (int fm = 0; fm < 4; ++fm)
        #pragma unroll
        for (int fn = 0; fn < 4; ++fn) {
            int o = o0 + wn*64 + fn*16 + (lane & 15);   // < 512 always
            float bias = bm[o];
            #pragma unroll
            for (int r = 0; r < 4; ++r) {
                int n = n0 + wm*64 + fm*16 + g4 + r;
                if (n < 207) out[((size_t)b*207 + n)*CO + o] = acc[fm][fn][r] + bias;
            }
        }
}

static inline size_t align_up(size_t v, size_t a) { return (v + a - 1) & ~(a - 1); }

extern "C" void kernel_launch(void* const* d_in, const int* in_sizes, int n_in,
                              void* d_out, int out_size, void* d_ws, size_t ws_size,
                              hipStream_t stream) {
    const float* x     = (const float*)d_in[0];
    const float* nv1   = (const float*)d_in[1];
    const float* nv2   = (const float*)d_in[2];
    const float* Wg    = (const float*)d_in[3];
    const float* bg    = (const float*)d_in[4];
    const float* gamma = (const float*)d_in[5];
    const float* beta  = (const float*)d_in[6];
    const float* rmean = (const float*)d_in[7];
    const float* rvar  = (const float*)d_in[8];
    const float* Wm    = (const float*)d_in[9];
    const float* bm    = (const float*)d_in[10];
    float* out = (float*)d_out;

    char* ws = (char*)d_ws;
    const size_t bufN = (size_t)B*ROWS*STRIDE*sizeof(ushort);   // 47.7 MB
    ushort* P1   = (ushort*)ws; ws += align_up((size_t)STRIDE*STRIDE*2, 512);
    ushort* P2   = (ushort*)ws; ws += align_up((size_t)STRIDE*STRIDE*2, 512);
    float* binv  = (float*)ws;  ws += align_up((size_t)NLAYERS*ROWS*4, 512);
    float* bfold = (float*)ws;  ws += align_up((size_t)NLAYERS*ROWS*4, 512);
    ushort* Wgp  = (ushort*)ws; ws += align_up((size_t)NLAYERS*3*ROWS*STRIDE*2, 512);
    ushort* Wmp  = (ushort*)ws; ws += align_up((size_t)CO*STRIDE*2, 512);
    ushort* buf0 = (ushort*)ws; ws += align_up(bufN, 512);   // Hcv-class
    ushort* buf1 = (ushort*)ws; ws += align_up(bufN, 512);   // Hnc-class
    ushort* buf2 = (ushort*)ws; ws += align_up(bufN, 512);   // X1
    ushort* buf3 = (ushort*)ws; ws += align_up(bufN, 512);   // X2

    // --- prep ---
    adp_kernel<<<STRIDE, 256, 0, stream>>>(nv1, nv2, P1);
    p2_kernel<<<dim3(14, 14), dim3(16, 16), 0, stream>>>(P1, P2);
    bn_kernel<<<(NLAYERS*ROWS + 255)/256, 256, 0, stream>>>(gamma, beta, rmean, rvar, bg, binv, bfold);
    wg_prep<<<(NLAYERS*3*ROWS*STRIDE + 255)/256, 256, 0, stream>>>(Wg, Wgp);
    wm_prep<<<(CO*STRIDE + 255)/256, 256, 0, stream>>>(Wm, Wmp);
    h0_kernel<<<dim3(7, 7, B), dim3(32, 8), 0, stream>>>(x, buf0, buf1);

    // --- layer 0 ---
    diffuse_kernel<<<dim3(2, 2, B), 256, 0, stream>>>(buf0, P1, P2, buf2, buf3);
    gconv_kernel<<<dim3(2, 2, B), 256, 0, stream>>>(buf1, buf2, buf3, Wgp, binv, bfold, 0, buf0); // H1cv -> buf0
    tr_kernel<<<dim3(7, 7, B), dim3(32, 8), 0, stream>>>(buf0, buf1);                             // H1nc -> buf1

    // --- layer 1 ---
    diffuse_kernel<<<dim3(2, 2, B), 256, 0, stream>>>(buf0, P1, P2, buf2, buf3);
    gconv_kernel<<<dim3(2, 2, B), 256, 0, stream>>>(buf1, buf2, buf3, Wgp, binv, bfold, 1, buf0); // H2cv -> buf0
    tr_kernel<<<dim3(7, 7, B), dim3(32, 8), 0, stream>>>(buf0, buf1);                             // H2nc -> buf1

    // --- final ---
    final_kernel<<<dim3(2, 4, B), 256, 0, stream>>>(buf1, Wmp, bm, out);
}

// Round 4
// 498.687 us; speedup vs baseline: 9.1927x; 1.0596x over previous
//
#include <hip/hip_runtime.h>
#include <hip/hip_bf16.h>

#define B 512
#define N 207
#define C 207
#define CO 512
#define NLAYERS 2
#define EPS 1e-5f

#define STRIDE 224      // padded inner dim (elements)
#define ROWS 208        // padded row count for H-class buffers
#define KSTEPS 7        // 224/32

typedef unsigned short ushort;
typedef short s8v __attribute__((ext_vector_type(8)));
typedef float f4 __attribute__((ext_vector_type(4)));
typedef unsigned short u16x4 __attribute__((ext_vector_type(4)));

__device__ __forceinline__ ushort f2bu(float f) {
    __hip_bfloat16 h = __float2bfloat16(f);
    return __builtin_bit_cast(ushort, h);
}
__device__ __forceinline__ float bu2f(ushort u) {
    union { unsigned int u; float f; } v; v.u = ((unsigned int)u) << 16;
    return v.f;
}
__device__ __forceinline__ u16x4 packbf4(f4 v) {
    u16x4 r;
    #pragma unroll
    for (int i = 0; i < 4; ++i) r[i] = f2bu(v[i]);
    return r;
}

// ---------------------------------------------------------------------------
// P1[w][v] = softmax_j(relu(nv1[w,:]@nv2[:,j]))[v]  (row-major (w,v), bf16,
// padded 224x224 with zeros). One block per row w (224 blocks).
// ---------------------------------------------------------------------------
__global__ void adp_kernel(const float* __restrict__ nv1, const float* __restrict__ nv2,
                           ushort* __restrict__ P1) {
    int w = blockIdx.x, j = threadIdx.x;
    __shared__ float red[256];
    if (w >= 207) {                      // zero pad rows
        if (j < STRIDE) P1[w*STRIDE + j] = 0;
        return;
    }
    float val = 0.f;
    if (j < 207) {
        float acc = 0.f;
        #pragma unroll
        for (int k = 0; k < 10; ++k) acc += nv1[w*10 + k] * nv2[k*207 + j];
        val = fmaxf(acc, 0.f);
    }
    red[j] = (j < 207) ? val : -1e30f;
    __syncthreads();
    for (int off = 128; off > 0; off >>= 1) {
        if (j < off) red[j] = fmaxf(red[j], red[j+off]);
        __syncthreads();
    }
    float m = red[0];
    __syncthreads();
    float e = (j < 207) ? expf(val - m) : 0.f;
    red[j] = e;
    __syncthreads();
    for (int off = 128; off > 0; off >>= 1) {
        if (j < off) red[j] += red[j+off];
        __syncthreads();
    }
    float inv = 1.f / red[0];
    if (j < STRIDE) P1[w*STRIDE + j] = f2bu(e * inv);
}

// P2 = P1 @ P1  (row-major (w,v)); pads come out zero automatically
__global__ void p2_kernel(const ushort* __restrict__ P1, ushort* __restrict__ P2) {
    int v = blockIdx.x*16 + threadIdx.x;
    int w = blockIdx.y*16 + threadIdx.y;
    if (w < STRIDE && v < STRIDE) {
        float acc = 0.f;
        for (int u = 0; u < 207; ++u) acc += bu2f(P1[w*STRIDE + u]) * bu2f(P1[u*STRIDE + v]);
        P2[w*STRIDE + v] = f2bu(acc);
    }
}

// BN fold, padded to 208: binv[o>=207]=0, bfold[o>=207]=0
__global__ void bn_kernel(const float* __restrict__ gamma, const float* __restrict__ beta,
                          const float* __restrict__ rmean, const float* __restrict__ rvar,
                          const float* __restrict__ bg,
                          float* __restrict__ binv, float* __restrict__ bfold) {
    int i = blockIdx.x*256 + threadIdx.x;
    if (i >= NLAYERS*ROWS) return;
    int l = i / ROWS, o = i % ROWS;
    float iv = 0.f, bf = 0.f;
    if (o < 207) {
        float g = gamma[l*207 + o];
        iv = g * rsqrtf(rvar[l*207 + o] + EPS);
        bf = bg[l*207 + o]*iv + beta[l*207 + o] - rmean[l*207 + o]*iv;
    }
    binv[i] = iv; bfold[i] = bf;
}

// Wg (L,207,621) f32 -> Wgp (L,3,208,224) bf16 zero-padded
__global__ void wg_prep(const float* __restrict__ Wg, ushort* __restrict__ Wgp) {
    int idx = blockIdx.x*256 + threadIdx.x;
    if (idx >= NLAYERS*3*ROWS*STRIDE) return;
    int k = idx % STRIDE;
    int o = (idx / STRIDE) % ROWS;
    int seg = (idx / (STRIDE*ROWS)) % 3;
    int l = idx / (STRIDE*ROWS*3);
    float v = (o < 207 && k < 207) ? Wg[((size_t)(l*207 + o))*621 + seg*207 + k] : 0.f;
    Wgp[idx] = f2bu(v);
}

// Wm (512,207) f32 -> Wmp (512,224) bf16 zero-padded
__global__ void wm_prep(const float* __restrict__ Wm, ushort* __restrict__ Wmp) {
    int idx = blockIdx.x*256 + threadIdx.x;
    if (idx >= CO*STRIDE) return;
    int k = idx % STRIDE, o = idx / STRIDE;
    Wmp[idx] = f2bu(k < 207 ? Wm[o*207 + k] : 0.f);
}

// x (B,207,207) f32 -> Hcv (B,208,224) [c][n]  AND  Hnc (B,208,224) [n][c]
// single read of x, dual-layout write
__global__ void h0_kernel(const float* __restrict__ x, ushort* __restrict__ Hcv,
                          ushort* __restrict__ Hnc) {
    __shared__ float t[32][33];
    int b = blockIdx.z;
    int n0 = blockIdx.x*32, c0 = blockIdx.y*32;
    int tx = threadIdx.x, ty = threadIdx.y;
    for (int i = ty; i < 32; i += 8) {
        int n = n0 + i, c = c0 + tx;
        t[i][tx] = (n < 207 && c < 207) ? x[((size_t)b*207 + n)*207 + c] : 0.f;
    }
    __syncthreads();
    size_t base = (size_t)b*ROWS*STRIDE;
    for (int i = ty; i < 32; i += 8) {
        int n = n0 + i, c = c0 + tx;
        if (n < ROWS && c < STRIDE) Hnc[base + (size_t)n*STRIDE + c] = f2bu(t[i][tx]);
    }
    for (int i = ty; i < 32; i += 8) {
        int c = c0 + i, n = n0 + tx;
        if (c < ROWS && n < STRIDE) Hcv[base + (size_t)c*STRIDE + n] = f2bu(t[tx][i]);
    }
}

// bf16 transpose: out[n][c] = in[c][n], per batch (208x224 padded both sides)
__global__ void tr_kernel(const ushort* __restrict__ in, ushort* __restrict__ out) {
    __shared__ ushort t[32][33];
    int b = blockIdx.z;
    size_t base = (size_t)b*ROWS*STRIDE;
    int n0 = blockIdx.x*32, c0 = blockIdx.y*32;
    int tx = threadIdx.x, ty = threadIdx.y;
    for (int i = ty; i < 32; i += 8) {
        int c = c0 + i, n = n0 + tx;
        t[i][tx] = (c < ROWS && n < STRIDE) ? in[base + (size_t)c*STRIDE + n] : 0;
    }
    __syncthreads();
    for (int i = ty; i < 32; i += 8) {
        int n = n0 + i, c = c0 + tx;
        if (n < ROWS && c < STRIDE) out[base + (size_t)n*STRIDE + c] = t[tx][i];
    }
}

// ---------------------------------------------------------------------------
// async staging: 128x32 bf16 tile via global_load_lds (16B/lane).
// LDS layout is linear in lane order: per wave, base + lane*16B.
// rows clamped to rmax (clamped rows must be zero rows in src).
// ---------------------------------------------------------------------------
__device__ __forceinline__ void stage_async(ushort* __restrict__ tile,
                                            const ushort* __restrict__ src,
                                            int rbase, int rmax, int kbase, int tid) {
    int lane = tid & 63, wave = tid >> 6;
    #pragma unroll
    for (int i = 0; i < 2; ++i) {
        int r = rbase + i*64 + wave*16 + (lane >> 2);
        r = (r > rmax) ? rmax : r;
        const ushort* g = src + (size_t)r*STRIDE + kbase + (lane & 3)*8;
        ushort* l = tile + i*2048 + wave*512;          // wave-uniform base
        __builtin_amdgcn_global_load_lds(
            (const __attribute__((address_space(1))) void*)g,
            (__attribute__((address_space(3))) void*)l, 16, 0, 0);
    }
}

// ---------------------------------------------------------------------------
// diffuse: X1[w][c] = sum_v P1[w][v]*Hcv[c][v]; X2 same with P2. Shared B tile.
// block tile 128x128, 4 waves 2x2, wave tile 64x64.
// MFMA operand-swapped: D fragment has col=lane&15 -> w (fixed per lane),
// reg quad -> 4 consecutive c  => one 8B store per fragment.
// ---------------------------------------------------------------------------
__global__ __launch_bounds__(256, 2)
void diffuse_kernel(const ushort* __restrict__ Hcv, const ushort* __restrict__ P1,
                    const ushort* __restrict__ P2,
                    ushort* __restrict__ X1, ushort* __restrict__ X2) {
    __shared__ __align__(16) ushort A1t[128*32], A2t[128*32], Bt[128*32];
    int b = blockIdx.z;
    int w0 = blockIdx.x*128, c0 = blockIdx.y*128;
    const ushort* Hb = Hcv + (size_t)b*ROWS*STRIDE;
    int tid = threadIdx.x, lane = tid & 63, wid = tid >> 6;
    int wm = wid >> 1, wn = wid & 1;
    int frow = lane & 15, fko = (lane >> 4)*8;

    f4 acc1[4][4], acc2[4][4];
    #pragma unroll
    for (int i = 0; i < 4; ++i)
        #pragma unroll
        for (int j = 0; j < 4; ++j) { acc1[i][j] = (f4)0.f; acc2[i][j] = (f4)0.f; }

    for (int ks = 0; ks < KSTEPS; ++ks) {
        int k0 = ks*32;
        stage_async(A1t, P1, w0, 223, k0, tid);
        stage_async(A2t, P2, w0, 223, k0, tid);
        stage_async(Bt,  Hb, c0, 207, k0, tid);
        __syncthreads();
        s8v a1[4], a2[4], bf[4];
        #pragma unroll
        for (int f = 0; f < 4; ++f) {
            a1[f] = *(const s8v*)&A1t[(wm*64 + f*16 + frow)*32 + fko];
            a2[f] = *(const s8v*)&A2t[(wm*64 + f*16 + frow)*32 + fko];
            bf[f] = *(const s8v*)&Bt [(wn*64 + f*16 + frow)*32 + fko];
        }
        #pragma unroll
        for (int fm = 0; fm < 4; ++fm)
            #pragma unroll
            for (int fn = 0; fn < 4; ++fn) {
                acc1[fm][fn] = __builtin_amdgcn_mfma_f32_16x16x32_bf16(bf[fn], a1[fm], acc1[fm][fn], 0, 0, 0);
                acc2[fm][fn] = __builtin_amdgcn_mfma_f32_16x16x32_bf16(bf[fn], a2[fm], acc2[fm][fn], 0, 0, 0);
            }
        __syncthreads();
    }

    ushort* X1b = X1 + (size_t)b*ROWS*STRIDE;
    ushort* X2b = X2 + (size_t)b*ROWS*STRIDE;
    int g4 = (lane >> 4)*4;
    #pragma unroll
    for (int fm = 0; fm < 4; ++fm) {
        int w = w0 + wm*64 + fm*16 + (lane & 15);
        if (w >= ROWS) continue;
        #pragma unroll
        for (int fn = 0; fn < 4; ++fn) {
            int cq = c0 + wn*64 + fn*16 + g4;       // 4-aligned quad base
            if (cq >= STRIDE) continue;
            *(u16x4*)(X1b + (size_t)w*STRIDE + cq) = packbf4(acc1[fm][fn]);
            *(u16x4*)(X2b + (size_t)w*STRIDE + cq) = packbf4(acc2[fm][fn]);
        }
    }
}

// ---------------------------------------------------------------------------
// gconv: Hout[o][n] = BN( sum_c' Wg[o][c'] * cat[c'][n] + bg )
// A = Wgp (o,k), B = {Hnc,X1,X2} (n,k). Swapped MFMA: lane holds o fixed,
// reg quad -> 4 consecutive n  => 8B store into (o,n)-major Hcv layout.
// ---------------------------------------------------------------------------
__global__ __launch_bounds__(256, 2)
void gconv_kernel(const ushort* __restrict__ Hnc, const ushort* __restrict__ X1,
                  const ushort* __restrict__ X2, const ushort* __restrict__ Wgp,
                  const float* __restrict__ binv, const float* __restrict__ bfold,
                  int layer, ushort* __restrict__ Hout) {
    __shared__ __align__(16) ushort At[128*32], Bt[128*32];
    int b = blockIdx.z;
    int o0 = blockIdx.x*128, n0 = blockIdx.y*128;
    size_t boff = (size_t)b*ROWS*STRIDE;
    const ushort* srcs[3] = { Hnc + boff, X1 + boff, X2 + boff };
    int tid = threadIdx.x, lane = tid & 63, wid = tid >> 6;
    int wm = wid >> 1, wn = wid & 1;
    int frow = lane & 15, fko = (lane >> 4)*8;

    f4 acc[4][4];
    #pragma unroll
    for (int i = 0; i < 4; ++i)
        #pragma unroll
        for (int j = 0; j < 4; ++j) acc[i][j] = (f4)0.f;

    for (int ks = 0; ks < 3*KSTEPS; ++ks) {
        int seg = ks / KSTEPS;
        int k0 = (ks % KSTEPS)*32;
        const ushort* As = Wgp + (size_t)(layer*3 + seg)*ROWS*STRIDE;
        stage_async(At, As, o0, 207, k0, tid);
        stage_async(Bt, srcs[seg], n0, 207, k0, tid);
        __syncthreads();
        s8v a[4], bf[4];
        #pragma unroll
        for (int f = 0; f < 4; ++f) {
            a[f]  = *(const s8v*)&At[(wm*64 + f*16 + frow)*32 + fko];
            bf[f] = *(const s8v*)&Bt[(wn*64 + f*16 + frow)*32 + fko];
        }
        #pragma unroll
        for (int fm = 0; fm < 4; ++fm)
            #pragma unroll
            for (int fn = 0; fn < 4; ++fn)
                acc[fm][fn] = __builtin_amdgcn_mfma_f32_16x16x32_bf16(bf[fn], a[fm], acc[fm][fn], 0, 0, 0);
        __syncthreads();
    }

    ushort* Ob = Hout + boff;
    const float* bi  = binv  + layer*ROWS;
    const float* bsh = bfold + layer*ROWS;
    int g4 = (lane >> 4)*4;
    #pragma unroll
    for (int fm = 0; fm < 4; ++fm) {
        int o = o0 + wm*64 + fm*16 + (lane & 15);
        if (o >= ROWS) continue;                    // rows >=208 of padded grid: no store
        float iv = bi[o], sh = bsh[o];              // o==207 -> iv=sh=0 -> zero row
        #pragma unroll
        for (int fn = 0; fn < 4; ++fn) {
            int nq = n0 + wn*64 + fn*16 + g4;
            if (nq >= STRIDE) continue;
            f4 h = acc[fm][fn]*iv + sh;
            *(u16x4*)(Ob + (size_t)o*STRIDE + nq) = packbf4(h);
        }
    }
}

// ---------------------------------------------------------------------------
// final: out[b][n][o] = sum_c Hnc[n][c]*Wm[o][c] + bm[o]
// Swapped MFMA: lane holds n fixed, reg quad -> 4 consecutive o
// => one float4 (16B) store per fragment, contiguous in output.
// ---------------------------------------------------------------------------
__global__ __launch_bounds__(256, 2)
void final_kernel(const ushort* __restrict__ Hnc, const ushort* __restrict__ Wmp,
                  const float* __restrict__ bm, float* __restrict__ out) {
    __shared__ __align__(16) ushort At[128*32], Bt[128*32];
    int b = blockIdx.z;
    int n0 = blockIdx.x*128, o0 = blockIdx.y*128;
    const ushort* Hb = Hnc + (size_t)b*ROWS*STRIDE;
    int tid = threadIdx.x, lane = tid & 63, wid = tid >> 6;
    int wm = wid >> 1, wn = wid & 1;
    int frow = lane & 15, fko = (lane >> 4)*8;

    f4 acc[4][4];
    #pragma unroll
    for (int i = 0; i < 4; ++i)
        #pragma unroll
        for (int j = 0; j < 4; ++j) acc[i][j] = (f4)0.f;

    for (int ks = 0; ks < KSTEPS; ++ks) {
        int k0 = ks*32;
        stage_async(At, Hb,  n0, 207, k0, tid);
        stage_async(Bt, Wmp, o0, 511, k0, tid);
        __syncthreads();
        s8v a[4], bf[4];
        #pragma unroll
        for (int f = 0; f < 4; ++f) {
            a[f]  = *(const s8v*)&At[(wm*64 + f*16 + frow)*32 + fko];
            bf[f] = *(const s8v*)&Bt[(wn*64 + f*16 + frow)*32 + fko];
        }
        #pragma unroll
        for (int fm = 0; fm < 4; ++fm)
            #pragma unroll
            for (int fn = 0; fn < 4; ++fn)
                acc[fm][fn] = __builtin_amdgcn_mfma_f32_16x16x32_bf16(bf[fn], a[fm], acc[fm][fn], 0, 0, 0);
        __syncthreads();
    }

    int g4 = (lane >> 4)*4;
    #pragma unroll
    for (int fm = 0; fm < 4; ++fm) {
        int n = n0 + wm*64 + fm*16 + (lane & 15);
        if (n >= 207) continue;
        float* orow = out + ((size_t)b*207 + n)*CO;
        #pragma unroll
        for (int fn = 0; fn < 4; ++fn) {
            int oq = o0 + wn*64 + fn*16 + g4;       // < 512 always, 4-aligned
            f4 bias = *(const f4*)(bm + oq);
            f4 v = acc[fm][fn] + bias;
            *(f4*)(orow + oq) = v;
        }
    }
}

static inline size_t align_up(size_t v, size_t a) { return (v + a - 1) & ~(a - 1); }

extern "C" void kernel_launch(void* const* d_in, const int* in_sizes, int n_in,
                              void* d_out, int out_size, void* d_ws, size_t ws_size,
                              hipStream_t stream) {
    const float* x     = (const float*)d_in[0];
    const float* nv1   = (const float*)d_in[1];
    const float* nv2   = (const float*)d_in[2];
    const float* Wg    = (const float*)d_in[3];
    const float* bg    = (const float*)d_in[4];
    const float* gamma = (const float*)d_in[5];
    const float* beta  = (const float*)d_in[6];
    const float* rmean = (const float*)d_in[7];
    const float* rvar  = (const float*)d_in[8];
    const float* Wm    = (const float*)d_in[9];
    const float* bm    = (const float*)d_in[10];
    float* out = (float*)d_out;

    char* ws = (char*)d_ws;
    const size_t bufN = (size_t)B*ROWS*STRIDE*sizeof(ushort);   // 47.7 MB
    ushort* P1   = (ushort*)ws; ws += align_up((size_t)STRIDE*STRIDE*2, 512);
    ushort* P2   = (ushort*)ws; ws += align_up((size_t)STRIDE*STRIDE*2, 512);
    float* binv  = (float*)ws;  ws += align_up((size_t)NLAYERS*ROWS*4, 512);
    float* bfold = (float*)ws;  ws += align_up((size_t)NLAYERS*ROWS*4, 512);
    ushort* Wgp  = (ushort*)ws; ws += align_up((size_t)NLAYERS*3*ROWS*STRIDE*2, 512);
    ushort* Wmp  = (ushort*)ws; ws += align_up((size_t)CO*STRIDE*2, 512);
    ushort* buf0 = (ushort*)ws; ws += align_up(bufN, 512);   // Hcv-class
    ushort* buf1 = (ushort*)ws; ws += align_up(bufN, 512);   // Hnc-class
    ushort* buf2 = (ushort*)ws; ws += align_up(bufN, 512);   // X1
    ushort* buf3 = (ushort*)ws; ws += align_up(bufN, 512);   // X2

    // --- prep ---
    adp_kernel<<<STRIDE, 256, 0, stream>>>(nv1, nv2, P1);
    p2_kernel<<<dim3(14, 14), dim3(16, 16), 0, stream>>>(P1, P2);
    bn_kernel<<<(NLAYERS*ROWS + 255)/256, 256, 0, stream>>>(gamma, beta, rmean, rvar, bg, binv, bfold);
    wg_prep<<<(NLAYERS*3*ROWS*STRIDE + 255)/256, 256, 0, stream>>>(Wg, Wgp);
    wm_prep<<<(CO*STRIDE + 255)/256, 256, 0, stream>>>(Wm, Wmp);
    h0_kernel<<<dim3(7, 7, B), dim3(32, 8), 0, stream>>>(x, buf0, buf1);

    // --- layer 0 ---
    diffuse_kernel<<<dim3(2, 2, B), 256, 0, stream>>>(buf0, P1, P2, buf2, buf3);
    gconv_kernel<<<dim3(2, 2, B), 256, 0, stream>>>(buf1, buf2, buf3, Wgp, binv, bfold, 0, buf0); // H1cv -> buf0
    tr_kernel<<<dim3(7, 7, B), dim3(32, 8), 0, stream>>>(buf0, buf1);                             // H1nc -> buf1

    // --- layer 1 ---
    diffuse_kernel<<<dim3(2, 2, B), 256, 0, stream>>>(buf0, P1, P2, buf2, buf3);
    gconv_kernel<<<dim3(2, 2, B), 256, 0, stream>>>(buf1, buf2, buf3, Wgp, binv, bfold, 1, buf0); // H2cv -> buf0
    tr_kernel<<<dim3(7, 7, B), dim3(32, 8), 0, stream>>>(buf0, buf1);                             // H2nc -> buf1

    // --- final ---
    final_kernel<<<dim3(2, 4, B), 256, 0, stream>>>(buf1, Wmp, bm, out);
}

// Round 5
// 494.156 us; speedup vs baseline: 9.2770x; 1.0092x over previous
//
#include <hip/hip_runtime.h>
#include <hip/hip_bf16.h>

#define B 512
#define N 207
#define C 207
#define CO 512
#define NLAYERS 2
#define EPS 1e-5f

#define STRIDE 224      // padded inner dim (elements)
#define ROWS 208        // padded row count for H-class buffers
#define KSTEPS 7        // 224/32
#define RS ((size_t)ROWS*STRIDE)

typedef unsigned short ushort;
typedef short s8v __attribute__((ext_vector_type(8)));
typedef float f4 __attribute__((ext_vector_type(4)));
typedef unsigned short u16x4 __attribute__((ext_vector_type(4)));

__device__ __forceinline__ ushort f2bu(float f) {
    __hip_bfloat16 h = __float2bfloat16(f);
    return __builtin_bit_cast(ushort, h);
}
__device__ __forceinline__ float bu2f(ushort u) {
    union { unsigned int u; float f; } v; v.u = ((unsigned int)u) << 16;
    return v.f;
}
__device__ __forceinline__ u16x4 packbf4(f4 v) {
    u16x4 r;
    #pragma unroll
    for (int i = 0; i < 4; ++i) r[i] = f2bu(v[i]);
    return r;
}

// ---------------------------------------------------------------------------
// P1[w][v] = softmax_j(relu(nv1[w,:]@nv2[:,j]))[v]  (row-major, bf16, 224x224
// zero-padded). One block per row w.
// ---------------------------------------------------------------------------
__global__ void adp_kernel(const float* __restrict__ nv1, const float* __restrict__ nv2,
                           ushort* __restrict__ P1) {
    int w = blockIdx.x, j = threadIdx.x;
    __shared__ float red[256];
    if (w >= 207) {
        if (j < STRIDE) P1[w*STRIDE + j] = 0;
        return;
    }
    float val = 0.f;
    if (j < 207) {
        float acc = 0.f;
        #pragma unroll
        for (int k = 0; k < 10; ++k) acc += nv1[w*10 + k] * nv2[k*207 + j];
        val = fmaxf(acc, 0.f);
    }
    red[j] = (j < 207) ? val : -1e30f;
    __syncthreads();
    for (int off = 128; off > 0; off >>= 1) {
        if (j < off) red[j] = fmaxf(red[j], red[j+off]);
        __syncthreads();
    }
    float m = red[0];
    __syncthreads();
    float e = (j < 207) ? expf(val - m) : 0.f;
    red[j] = e;
    __syncthreads();
    for (int off = 128; off > 0; off >>= 1) {
        if (j < off) red[j] += red[j+off];
        __syncthreads();
    }
    float inv = 1.f / red[0];
    if (j < STRIDE) P1[w*STRIDE + j] = f2bu(e * inv);
}

// P2 = P1 @ P1
__global__ void p2_kernel(const ushort* __restrict__ P1, ushort* __restrict__ P2) {
    int v = blockIdx.x*16 + threadIdx.x;
    int w = blockIdx.y*16 + threadIdx.y;
    if (w < STRIDE && v < STRIDE) {
        float acc = 0.f;
        for (int u = 0; u < 207; ++u) acc += bu2f(P1[w*STRIDE + u]) * bu2f(P1[u*STRIDE + v]);
        P2[w*STRIDE + v] = f2bu(acc);
    }
}

// BN fold, padded: binv[o>=207]=0, bfold[o>=207]=0
__global__ void bn_kernel(const float* __restrict__ gamma, const float* __restrict__ beta,
                          const float* __restrict__ rmean, const float* __restrict__ rvar,
                          const float* __restrict__ bg,
                          float* __restrict__ binv, float* __restrict__ bfold) {
    int i = blockIdx.x*256 + threadIdx.x;
    if (i >= NLAYERS*ROWS) return;
    int l = i / ROWS, o = i % ROWS;
    float iv = 0.f, bf = 0.f;
    if (o < 207) {
        float g = gamma[l*207 + o];
        iv = g * rsqrtf(rvar[l*207 + o] + EPS);
        bf = bg[l*207 + o]*iv + beta[l*207 + o] - rmean[l*207 + o]*iv;
    }
    binv[i] = iv; bfold[i] = bf;
}

// Wg (L,207,621) f32 -> Wgp (L,3,208,224) bf16 zero-padded
__global__ void wg_prep(const float* __restrict__ Wg, ushort* __restrict__ Wgp) {
    int idx = blockIdx.x*256 + threadIdx.x;
    if (idx >= NLAYERS*3*ROWS*STRIDE) return;
    int k = idx % STRIDE;
    int o = (idx / STRIDE) % ROWS;
    int seg = (idx / (STRIDE*ROWS)) % 3;
    int l = idx / (STRIDE*ROWS*3);
    float v = (o < 207 && k < 207) ? Wg[((size_t)(l*207 + o))*621 + seg*207 + k] : 0.f;
    Wgp[idx] = f2bu(v);
}

// Wm (512,207) f32 -> Wmp (512,224) bf16 zero-padded
__global__ void wm_prep(const float* __restrict__ Wm, ushort* __restrict__ Wmp) {
    int idx = blockIdx.x*256 + threadIdx.x;
    if (idx >= CO*STRIDE) return;
    int k = idx % STRIDE, o = idx / STRIDE;
    Wmp[idx] = f2bu(k < 207 ? Wm[o*207 + k] : 0.f);
}

// x (B,207,207) f32 -> Hcv [c][n]  AND  Hnc [n][c]  (both 208x224, zero-padded)
__global__ void h0_kernel(const float* __restrict__ x, ushort* __restrict__ Hcv,
                          ushort* __restrict__ Hnc) {
    __shared__ float t[32][33];
    int b = blockIdx.z;
    int n0 = blockIdx.x*32, c0 = blockIdx.y*32;
    int tx = threadIdx.x, ty = threadIdx.y;
    for (int i = ty; i < 32; i += 8) {
        int n = n0 + i, c = c0 + tx;
        t[i][tx] = (n < 207 && c < 207) ? x[((size_t)b*207 + n)*207 + c] : 0.f;
    }
    __syncthreads();
    size_t base = (size_t)b*RS;
    for (int i = ty; i < 32; i += 8) {
        int n = n0 + i, c = c0 + tx;
        if (n < ROWS && c < STRIDE) Hnc[base + (size_t)n*STRIDE + c] = f2bu(t[i][tx]);
    }
    for (int i = ty; i < 32; i += 8) {
        int c = c0 + i, n = n0 + tx;
        if (c < ROWS && n < STRIDE) Hcv[base + (size_t)c*STRIDE + n] = f2bu(t[tx][i]);
    }
}

// ---------------------------------------------------------------------------
// async staging: 128x32 bf16 tile via global_load_lds (16B/lane).
// ---------------------------------------------------------------------------
__device__ __forceinline__ void stage_async(ushort* __restrict__ tile,
                                            const ushort* __restrict__ src,
                                            int rbase, int rmax, int kbase, int tid) {
    int lane = tid & 63, wave = tid >> 6;
    #pragma unroll
    for (int i = 0; i < 2; ++i) {
        int r = rbase + i*64 + wave*16 + (lane >> 2);
        r = (r > rmax) ? rmax : r;
        const ushort* g = src + (size_t)r*STRIDE + kbase + (lane & 3)*8;
        ushort* l = tile + i*2048 + wave*512;          // wave-uniform base
        __builtin_amdgcn_global_load_lds(
            (const __attribute__((address_space(1))) void*)g,
            (__attribute__((address_space(3))) void*)l, 16, 0, 0);
    }
}

#define WAIT_VM(n) asm volatile("s_waitcnt vmcnt(" #n ")" ::: "memory")
#define WAIT_LGKM0 asm volatile("s_waitcnt lgkmcnt(0)" ::: "memory")

// ---------------------------------------------------------------------------
// diffuse: X1[w][c] = sum_v P1[w][v]*Hcv[c][v]; X2 same with P2.
// 2-phase double-buffered K-loop, counted vmcnt. Swapped MFMA epilogue.
// ---------------------------------------------------------------------------
__global__ __launch_bounds__(256, 2)
void diffuse_kernel(const ushort* __restrict__ Hcv, const ushort* __restrict__ P1,
                    const ushort* __restrict__ P2,
                    ushort* __restrict__ X1, ushort* __restrict__ X2) {
    __shared__ __align__(16) ushort A1t[2][128*32], A2t[2][128*32], Bt[2][128*32];
    int b = blockIdx.z;
    int w0 = blockIdx.x*128, c0 = blockIdx.y*128;
    const ushort* Hb = Hcv + (size_t)b*RS;
    int tid = threadIdx.x, lane = tid & 63, wid = tid >> 6;
    int wm = wid >> 1, wn = wid & 1;
    int frow = lane & 15, fko = (lane >> 4)*8;

    f4 acc1[4][4], acc2[4][4];
    #pragma unroll
    for (int i = 0; i < 4; ++i)
        #pragma unroll
        for (int j = 0; j < 4; ++j) { acc1[i][j] = (f4)0.f; acc2[i][j] = (f4)0.f; }

    stage_async(A1t[0], P1, w0, 223, 0, tid);
    stage_async(A2t[0], P2, w0, 223, 0, tid);
    stage_async(Bt[0],  Hb, c0, 207, 0, tid);

    for (int ks = 0; ks < KSTEPS; ++ks) {
        int cur = ks & 1;
        if (ks + 1 < KSTEPS) {
            int k1 = (ks + 1)*32;
            stage_async(A1t[cur^1], P1, w0, 223, k1, tid);
            stage_async(A2t[cur^1], P2, w0, 223, k1, tid);
            stage_async(Bt[cur^1],  Hb, c0, 207, k1, tid);
            WAIT_VM(6);                 // cur's 6 loads done; next 6 in flight
        } else {
            WAIT_VM(0);
        }
        __builtin_amdgcn_s_barrier();
        s8v a1[4], a2[4], bf[4];
        #pragma unroll
        for (int f = 0; f < 4; ++f) {
            a1[f] = *(const s8v*)&A1t[cur][(wm*64 + f*16 + frow)*32 + fko];
            a2[f] = *(const s8v*)&A2t[cur][(wm*64 + f*16 + frow)*32 + fko];
            bf[f] = *(const s8v*)&Bt [cur][(wn*64 + f*16 + frow)*32 + fko];
        }
        #pragma unroll
        for (int fm = 0; fm < 4; ++fm)
            #pragma unroll
            for (int fn = 0; fn < 4; ++fn) {
                acc1[fm][fn] = __builtin_amdgcn_mfma_f32_16x16x32_bf16(bf[fn], a1[fm], acc1[fm][fn], 0, 0, 0);
                acc2[fm][fn] = __builtin_amdgcn_mfma_f32_16x16x32_bf16(bf[fn], a2[fm], acc2[fm][fn], 0, 0, 0);
            }
        WAIT_LGKM0;
        __builtin_amdgcn_s_barrier();
    }

    ushort* X1b = X1 + (size_t)b*RS;
    ushort* X2b = X2 + (size_t)b*RS;
    int g4 = (lane >> 4)*4;
    #pragma unroll
    for (int fm = 0; fm < 4; ++fm) {
        int w = w0 + wm*64 + fm*16 + (lane & 15);
        if (w >= ROWS) continue;
        #pragma unroll
        for (int fn = 0; fn < 4; ++fn) {
            int cq = c0 + wn*64 + fn*16 + g4;
            if (cq >= STRIDE) continue;
            *(u16x4*)(X1b + (size_t)w*STRIDE + cq) = packbf4(acc1[fm][fn]);
            *(u16x4*)(X2b + (size_t)w*STRIDE + cq) = packbf4(acc2[fm][fn]);
        }
    }
}

// ---------------------------------------------------------------------------
// gconv: G[o][n] = BN( sum_c' Wg[o][c'] * cat[c'][n] + bg ).
// Dual-layout store: Hcv (o,n) quad stores + Hnc (n,o) scatter stores.
// ---------------------------------------------------------------------------
__global__ __launch_bounds__(256, 2)
void gconv_kernel(const ushort* __restrict__ Hnc, const ushort* __restrict__ X1,
                  const ushort* __restrict__ X2, const ushort* __restrict__ Wgp,
                  const float* __restrict__ binv, const float* __restrict__ bfold,
                  int layer, ushort* __restrict__ Hcv_out, ushort* __restrict__ Hnc_out) {
    __shared__ __align__(16) ushort At[2][128*32], Bt[2][128*32];
    int b = blockIdx.z;
    int o0 = blockIdx.x*128, n0 = blockIdx.y*128;
    size_t boff = (size_t)b*RS;
    const ushort* src0 = Hnc + boff;
    const ushort* src1 = X1 + boff;
    const ushort* src2 = X2 + boff;
    const ushort* wbase = Wgp + (size_t)layer*3*RS;
    int tid = threadIdx.x, lane = tid & 63, wid = tid >> 6;
    int wm = wid >> 1, wn = wid & 1;
    int frow = lane & 15, fko = (lane >> 4)*8;

    f4 acc[4][4];
    #pragma unroll
    for (int i = 0; i < 4; ++i)
        #pragma unroll
        for (int j = 0; j < 4; ++j) acc[i][j] = (f4)0.f;

    stage_async(At[0], wbase, o0, 207, 0, tid);
    stage_async(Bt[0], src0,  n0, 207, 0, tid);

    const int NK = 3*KSTEPS;
    for (int ks = 0; ks < NK; ++ks) {
        int cur = ks & 1;
        if (ks + 1 < NK) {
            int ks1 = ks + 1;
            const ushort* bs = (ks1 < KSTEPS) ? src0 : ((ks1 < 2*KSTEPS) ? src1 : src2);
            int kk = (ks1 < KSTEPS) ? ks1 : ((ks1 < 2*KSTEPS) ? ks1 - KSTEPS : ks1 - 2*KSTEPS);
            stage_async(At[cur^1], wbase + (size_t)(ks1/KSTEPS)*RS, o0, 207, kk*32, tid);
            stage_async(Bt[cur^1], bs, n0, 207, kk*32, tid);
            WAIT_VM(4);
        } else {
            WAIT_VM(0);
        }
        __builtin_amdgcn_s_barrier();
        s8v a[4], bf[4];
        #pragma unroll
        for (int f = 0; f < 4; ++f) {
            a[f]  = *(const s8v*)&At[cur][(wm*64 + f*16 + frow)*32 + fko];
            bf[f] = *(const s8v*)&Bt[cur][(wn*64 + f*16 + frow)*32 + fko];
        }
        #pragma unroll
        for (int fm = 0; fm < 4; ++fm)
            #pragma unroll
            for (int fn = 0; fn < 4; ++fn)
                acc[fm][fn] = __builtin_amdgcn_mfma_f32_16x16x32_bf16(bf[fn], a[fm], acc[fm][fn], 0, 0, 0);
        WAIT_LGKM0;
        __builtin_amdgcn_s_barrier();
    }

    ushort* Ocv = Hcv_out + boff;
    ushort* Onc = Hnc_out + boff;
    const float* bi  = binv  + layer*ROWS;
    const float* bsh = bfold + layer*ROWS;
    int g4 = (lane >> 4)*4;
    #pragma unroll
    for (int fm = 0; fm < 4; ++fm) {
        int o = o0 + wm*64 + fm*16 + (lane & 15);
        if (o >= ROWS) continue;
        float iv = bi[o], sh = bsh[o];              // o==207 -> 0 -> zero row/col
        #pragma unroll
        for (int fn = 0; fn < 4; ++fn) {
            int nq = n0 + wn*64 + fn*16 + g4;
            if (nq >= STRIDE) continue;
            f4 h = acc[fm][fn]*iv + sh;
            u16x4 hq = packbf4(h);
            *(u16x4*)(Ocv + (size_t)o*STRIDE + nq) = hq;
            #pragma unroll
            for (int r = 0; r < 4; ++r) {
                int n = nq + r;
                if (n < ROWS) Onc[(size_t)n*STRIDE + o] = hq[r];
            }
        }
    }
}

// ---------------------------------------------------------------------------
// final: out[b][n][o] = sum_c Hnc[n][c]*Wm[o][c] + bm[o]
// ---------------------------------------------------------------------------
__global__ __launch_bounds__(256, 2)
void final_kernel(const ushort* __restrict__ Hnc, const ushort* __restrict__ Wmp,
                  const float* __restrict__ bm, float* __restrict__ out) {
    __shared__ __align__(16) ushort At[2][128*32], Bt[2][128*32];
    int b = blockIdx.z;
    int n0 = blockIdx.x*128, o0 = blockIdx.y*128;
    const ushort* Hb = Hnc + (size_t)b*RS;
    int tid = threadIdx.x, lane = tid & 63, wid = tid >> 6;
    int wm = wid >> 1, wn = wid & 1;
    int frow = lane & 15, fko = (lane >> 4)*8;

    f4 acc[4][4];
    #pragma unroll
    for (int i = 0; i < 4; ++i)
        #pragma unroll
        for (int j = 0; j < 4; ++j) acc[i][j] = (f4)0.f;

    stage_async(At[0], Hb,  n0, 207, 0, tid);
    stage_async(Bt[0], Wmp, o0, 511, 0, tid);

    for (int ks = 0; ks < KSTEPS; ++ks) {
        int cur = ks & 1;
        if (ks + 1 < KSTEPS) {
            int k1 = (ks + 1)*32;
            stage_async(At[cur^1], Hb,  n0, 207, k1, tid);
            stage_async(Bt[cur^1], Wmp, o0, 511, k1, tid);
            WAIT_VM(4);
        } else {
            WAIT_VM(0);
        }
        __builtin_amdgcn_s_barrier();
        s8v a[4], bf[4];
        #pragma unroll
        for (int f = 0; f < 4; ++f) {
            a[f]  = *(const s8v*)&At[cur][(wm*64 + f*16 + frow)*32 + fko];
            bf[f] = *(const s8v*)&Bt[cur][(wn*64 + f*16 + frow)*32 + fko];
        }
        #pragma unroll
        for (int fm = 0; fm < 4; ++fm)
            #pragma unroll
            for (int fn = 0; fn < 4; ++fn)
                acc[fm][fn] = __builtin_amdgcn_mfma_f32_16x16x32_bf16(bf[fn], a[fm], acc[fm][fn], 0, 0, 0);
        WAIT_LGKM0;
        __builtin_amdgcn_s_barrier();
    }

    int g4 = (lane >> 4)*4;
    #pragma unroll
    for (int fm = 0; fm < 4; ++fm) {
        int n = n0 + wm*64 + fm*16 + (lane & 15);
        if (n >= 207) continue;
        float* orow = out + ((size_t)b*207 + n)*CO;
        #pragma unroll
        for (int fn = 0; fn < 4; ++fn) {
            int oq = o0 + wn*64 + fn*16 + g4;
            f4 bias = *(const f4*)(bm + oq);
            f4 v = acc[fm][fn] + bias;
            *(f4*)(orow + oq) = v;
        }
    }
}

static inline size_t align_up(size_t v, size_t a) { return (v + a - 1) & ~(a - 1); }

extern "C" void kernel_launch(void* const* d_in, const int* in_sizes, int n_in,
                              void* d_out, int out_size, void* d_ws, size_t ws_size,
                              hipStream_t stream) {
    const float* x     = (const float*)d_in[0];
    const float* nv1   = (const float*)d_in[1];
    const float* nv2   = (const float*)d_in[2];
    const float* Wg    = (const float*)d_in[3];
    const float* bg    = (const float*)d_in[4];
    const float* gamma = (const float*)d_in[5];
    const float* beta  = (const float*)d_in[6];
    const float* rmean = (const float*)d_in[7];
    const float* rvar  = (const float*)d_in[8];
    const float* Wm    = (const float*)d_in[9];
    const float* bm    = (const float*)d_in[10];
    float* out = (float*)d_out;

    char* ws = (char*)d_ws;
    const size_t bufN = (size_t)B*RS*sizeof(ushort);   // 47.7 MB
    ushort* P1   = (ushort*)ws; ws += align_up((size_t)STRIDE*STRIDE*2, 512);
    ushort* P2   = (ushort*)ws; ws += align_up((size_t)STRIDE*STRIDE*2, 512);
    float* binv  = (float*)ws;  ws += align_up((size_t)NLAYERS*ROWS*4, 512);
    float* bfold = (float*)ws;  ws += align_up((size_t)NLAYERS*ROWS*4, 512);
    ushort* Wgp  = (ushort*)ws; ws += align_up((size_t)NLAYERS*3*RS*2, 512);
    ushort* Wmp  = (ushort*)ws; ws += align_up((size_t)CO*STRIDE*2, 512);
    ushort* A0 = (ushort*)ws; ws += align_up(bufN, 512);   // Hcv ping
    ushort* A1 = (ushort*)ws; ws += align_up(bufN, 512);   // Hnc ping
    ushort* B0 = (ushort*)ws; ws += align_up(bufN, 512);   // Hcv pong
    ushort* B1 = (ushort*)ws; ws += align_up(bufN, 512);   // Hnc pong
    ushort* X1 = (ushort*)ws; ws += align_up(bufN, 512);
    ushort* X2 = (ushort*)ws; ws += align_up(bufN, 512);

    // --- prep ---
    adp_kernel<<<STRIDE, 256, 0, stream>>>(nv1, nv2, P1);
    p2_kernel<<<dim3(14, 14), dim3(16, 16), 0, stream>>>(P1, P2);
    bn_kernel<<<(NLAYERS*ROWS + 255)/256, 256, 0, stream>>>(gamma, beta, rmean, rvar, bg, binv, bfold);
    wg_prep<<<(NLAYERS*3*ROWS*STRIDE + 255)/256, 256, 0, stream>>>(Wg, Wgp);
    wm_prep<<<(CO*STRIDE + 255)/256, 256, 0, stream>>>(Wm, Wmp);
    h0_kernel<<<dim3(7, 7, B), dim3(32, 8), 0, stream>>>(x, A0, A1);

    // --- layer 0 ---
    diffuse_kernel<<<dim3(2, 2, B), 256, 0, stream>>>(A0, P1, P2, X1, X2);
    gconv_kernel<<<dim3(2, 2, B), 256, 0, stream>>>(A1, X1, X2, Wgp, binv, bfold, 0, B0, B1);

    // --- layer 1 ---
    diffuse_kernel<<<dim3(2, 2, B), 256, 0, stream>>>(B0, P1, P2, X1, X2);
    gconv_kernel<<<dim3(2, 2, B), 256, 0, stream>>>(B1, X1, X2, Wgp, binv, bfold, 1, A0, A1);

    // --- final ---
    final_kernel<<<dim3(2, 4, B), 256, 0, stream>>>(A1, Wmp, bm, out);
}

// Round 6
// 486.024 us; speedup vs baseline: 9.4322x; 1.0167x over previous
//
#include <hip/hip_runtime.h>
#include <hip/hip_bf16.h>

#define B 512
#define N 207
#define C 207
#define CO 512
#define NLAYERS 2
#define EPS 1e-5f

#define STRIDE 224      // padded inner dim (elements)
#define ROWS 208        // padded row count for H-class buffers
#define KSTEPS 7        // 224/32
#define RS ((size_t)ROWS*STRIDE)

typedef unsigned short ushort;
typedef short s8v __attribute__((ext_vector_type(8)));
typedef float f4 __attribute__((ext_vector_type(4)));
typedef unsigned short u16x4 __attribute__((ext_vector_type(4)));

__device__ __forceinline__ ushort f2bu(float f) {
    __hip_bfloat16 h = __float2bfloat16(f);
    return __builtin_bit_cast(ushort, h);
}
__device__ __forceinline__ float bu2f(ushort u) {
    union { unsigned int u; float f; } v; v.u = ((unsigned int)u) << 16;
    return v.f;
}
__device__ __forceinline__ u16x4 packbf4(f4 v) {
    u16x4 r;
    #pragma unroll
    for (int i = 0; i < 4; ++i) r[i] = f2bu(v[i]);
    return r;
}

// ---------------------------------------------------------------------------
// P1[w][v] = softmax_j(relu(nv1[w,:]@nv2[:,j]))[v]  (row-major, bf16, 224x224
// zero-padded). One block per row w.
// ---------------------------------------------------------------------------
__global__ void adp_kernel(const float* __restrict__ nv1, const float* __restrict__ nv2,
                           ushort* __restrict__ P1) {
    int w = blockIdx.x, j = threadIdx.x;
    __shared__ float red[256];
    if (w >= 207) {
        if (j < STRIDE) P1[w*STRIDE + j] = 0;
        return;
    }
    float val = 0.f;
    if (j < 207) {
        float acc = 0.f;
        #pragma unroll
        for (int k = 0; k < 10; ++k) acc += nv1[w*10 + k] * nv2[k*207 + j];
        val = fmaxf(acc, 0.f);
    }
    red[j] = (j < 207) ? val : -1e30f;
    __syncthreads();
    for (int off = 128; off > 0; off >>= 1) {
        if (j < off) red[j] = fmaxf(red[j], red[j+off]);
        __syncthreads();
    }
    float m = red[0];
    __syncthreads();
    float e = (j < 207) ? expf(val - m) : 0.f;
    red[j] = e;
    __syncthreads();
    for (int off = 128; off > 0; off >>= 1) {
        if (j < off) red[j] += red[j+off];
        __syncthreads();
    }
    float inv = 1.f / red[0];
    if (j < STRIDE) P1[w*STRIDE + j] = f2bu(e * inv);
}

// P2 = P1 @ P1
__global__ void p2_kernel(const ushort* __restrict__ P1, ushort* __restrict__ P2) {
    int v = blockIdx.x*16 + threadIdx.x;
    int w = blockIdx.y*16 + threadIdx.y;
    if (w < STRIDE && v < STRIDE) {
        float acc = 0.f;
        for (int u = 0; u < 207; ++u) acc += bu2f(P1[w*STRIDE + u]) * bu2f(P1[u*STRIDE + v]);
        P2[w*STRIDE + v] = f2bu(acc);
    }
}

// BN fold, padded: binv[o>=207]=0, bfold[o>=207]=0
__global__ void bn_kernel(const float* __restrict__ gamma, const float* __restrict__ beta,
                          const float* __restrict__ rmean, const float* __restrict__ rvar,
                          const float* __restrict__ bg,
                          float* __restrict__ binv, float* __restrict__ bfold) {
    int i = blockIdx.x*256 + threadIdx.x;
    if (i >= NLAYERS*ROWS) return;
    int l = i / ROWS, o = i % ROWS;
    float iv = 0.f, bf = 0.f;
    if (o < 207) {
        float g = gamma[l*207 + o];
        iv = g * rsqrtf(rvar[l*207 + o] + EPS);
        bf = bg[l*207 + o]*iv + beta[l*207 + o] - rmean[l*207 + o]*iv;
    }
    binv[i] = iv; bfold[i] = bf;
}

// Wg (L,207,621) f32 -> Wgp (L,3,208,224) bf16 zero-padded
__global__ void wg_prep(const float* __restrict__ Wg, ushort* __restrict__ Wgp) {
    int idx = blockIdx.x*256 + threadIdx.x;
    if (idx >= NLAYERS*3*ROWS*STRIDE) return;
    int k = idx % STRIDE;
    int o = (idx / STRIDE) % ROWS;
    int seg = (idx / (STRIDE*ROWS)) % 3;
    int l = idx / (STRIDE*ROWS*3);
    float v = (o < 207 && k < 207) ? Wg[((size_t)(l*207 + o))*621 + seg*207 + k] : 0.f;
    Wgp[idx] = f2bu(v);
}

// Wm (512,207) f32 -> Wmp (512,224) bf16 zero-padded
__global__ void wm_prep(const float* __restrict__ Wm, ushort* __restrict__ Wmp) {
    int idx = blockIdx.x*256 + threadIdx.x;
    if (idx >= CO*STRIDE) return;
    int k = idx % STRIDE, o = idx / STRIDE;
    Wmp[idx] = f2bu(k < 207 ? Wm[o*207 + k] : 0.f);
}

// x (B,207,207) f32 -> Hcv [c][n]  AND  Hnc [n][c]  (both 208x224, zero-padded)
__global__ void h0_kernel(const float* __restrict__ x, ushort* __restrict__ Hcv,
                          ushort* __restrict__ Hnc) {
    __shared__ float t[32][33];
    int b = blockIdx.z;
    int n0 = blockIdx.x*32, c0 = blockIdx.y*32;
    int tx = threadIdx.x, ty = threadIdx.y;
    for (int i = ty; i < 32; i += 8) {
        int n = n0 + i, c = c0 + tx;
        t[i][tx] = (n < 207 && c < 207) ? x[((size_t)b*207 + n)*207 + c] : 0.f;
    }
    __syncthreads();
    size_t base = (size_t)b*RS;
    for (int i = ty; i < 32; i += 8) {
        int n = n0 + i, c = c0 + tx;
        if (n < ROWS && c < STRIDE) Hnc[base + (size_t)n*STRIDE + c] = f2bu(t[i][tx]);
    }
    for (int i = ty; i < 32; i += 8) {
        int c = c0 + i, n = n0 + tx;
        if (c < ROWS && n < STRIDE) Hcv[base + (size_t)c*STRIDE + n] = f2bu(t[tx][i]);
    }
}

// ---------------------------------------------------------------------------
// async staging for 512-thread blocks: ROUNDS_*128 rows x 32 cols bf16 tile
// via global_load_lds (16B/lane, wave-uniform LDS base + lane*16B).
// rows clamped to rmax (clamped rows must be zero rows in src).
// ---------------------------------------------------------------------------
template<int ROUNDS_>
__device__ __forceinline__ void stage512(ushort* __restrict__ tile,
                                         const ushort* __restrict__ src,
                                         int rbase, int rmax, int kbase, int tid) {
    int lane = tid & 63, wave = tid >> 6;   // 8 waves
    #pragma unroll
    for (int i = 0; i < ROUNDS_; ++i) {
        int r = rbase + i*128 + wave*16 + (lane >> 2);
        r = (r > rmax) ? rmax : r;
        const ushort* g = src + (size_t)r*STRIDE + kbase + (lane & 3)*8;
        ushort* l = tile + i*4096 + wave*512;          // wave-uniform base
        __builtin_amdgcn_global_load_lds(
            (const __attribute__((address_space(1))) void*)g,
            (__attribute__((address_space(3))) void*)l, 16, 0, 0);
    }
}

#define WAIT_VM(n) asm volatile("s_waitcnt vmcnt(" #n ")" ::: "memory")
#define WAIT_LGKM0 asm volatile("s_waitcnt lgkmcnt(0)" ::: "memory")

// ---------------------------------------------------------------------------
// diffuse: X1[w][c] = sum_v P1[w][v]*Hcv[c][v]; X2 same with P2.
// One block per (c-tile, batch): all 256 padded w rows, B (Hcv) staged once.
// 8 waves: wm=wid>>1 (w quad of 64), wn=wid&1 (c half of 64).
// ---------------------------------------------------------------------------
__global__ __launch_bounds__(512, 2)
void diffuse_kernel(const ushort* __restrict__ Hcv, const ushort* __restrict__ P1,
                    const ushort* __restrict__ P2,
                    ushort* __restrict__ X1, ushort* __restrict__ X2) {
    __shared__ __align__(16) ushort A1t[2][256*32], A2t[2][256*32], Bt[2][128*32];
    int b = blockIdx.y;
    int c0 = blockIdx.x*128;
    const ushort* Hb = Hcv + (size_t)b*RS;
    int tid = threadIdx.x, lane = tid & 63, wid = tid >> 6;
    int wm = wid >> 1, wn = wid & 1;
    int frow = lane & 15, fko = (lane >> 4)*8;

    f4 acc1[4][4], acc2[4][4];
    #pragma unroll
    for (int i = 0; i < 4; ++i)
        #pragma unroll
        for (int j = 0; j < 4; ++j) { acc1[i][j] = (f4)0.f; acc2[i][j] = (f4)0.f; }

    stage512<2>(A1t[0], P1, 0, 223, 0, tid);
    stage512<2>(A2t[0], P2, 0, 223, 0, tid);
    stage512<1>(Bt[0],  Hb, c0, 207, 0, tid);

    for (int ks = 0; ks < KSTEPS; ++ks) {
        int cur = ks & 1;
        if (ks + 1 < KSTEPS) {
            int k1 = (ks + 1)*32;
            stage512<2>(A1t[cur^1], P1, 0, 223, k1, tid);
            stage512<2>(A2t[cur^1], P2, 0, 223, k1, tid);
            stage512<1>(Bt[cur^1],  Hb, c0, 207, k1, tid);
            WAIT_VM(5);                 // this wave's cur loads done; next 5 in flight
        } else {
            WAIT_VM(0);
        }
        __builtin_amdgcn_s_barrier();
        s8v a1[4], a2[4], bf[4];
        #pragma unroll
        for (int f = 0; f < 4; ++f) {
            a1[f] = *(const s8v*)&A1t[cur][(wm*64 + f*16 + frow)*32 + fko];
            a2[f] = *(const s8v*)&A2t[cur][(wm*64 + f*16 + frow)*32 + fko];
            bf[f] = *(const s8v*)&Bt [cur][(wn*64 + f*16 + frow)*32 + fko];
        }
        #pragma unroll
        for (int fm = 0; fm < 4; ++fm)
            #pragma unroll
            for (int fn = 0; fn < 4; ++fn) {
                acc1[fm][fn] = __builtin_amdgcn_mfma_f32_16x16x32_bf16(bf[fn], a1[fm], acc1[fm][fn], 0, 0, 0);
                acc2[fm][fn] = __builtin_amdgcn_mfma_f32_16x16x32_bf16(bf[fn], a2[fm], acc2[fm][fn], 0, 0, 0);
            }
        WAIT_LGKM0;
        __builtin_amdgcn_s_barrier();
    }

    ushort* X1b = X1 + (size_t)b*RS;
    ushort* X2b = X2 + (size_t)b*RS;
    int g4 = (lane >> 4)*4;
    #pragma unroll
    for (int fm = 0; fm < 4; ++fm) {
        int w = wm*64 + fm*16 + (lane & 15);
        if (w >= ROWS) continue;
        #pragma unroll
        for (int fn = 0; fn < 4; ++fn) {
            int cq = c0 + wn*64 + fn*16 + g4;
            if (cq >= STRIDE) continue;
            *(u16x4*)(X1b + (size_t)w*STRIDE + cq) = packbf4(acc1[fm][fn]);
            *(u16x4*)(X2b + (size_t)w*STRIDE + cq) = packbf4(acc2[fm][fn]);
        }
    }
}

// ---------------------------------------------------------------------------
// gconv: G[o][n] = BN( sum_c' Wg[o][c'] * cat[c'][n] + bg ).
// One block per (n-tile, batch): all 256 padded o rows, B staged once.
// Dual-layout store: Hcv (o,n) quad stores + Hnc (n,o) scatter stores.
// ---------------------------------------------------------------------------
__global__ __launch_bounds__(512, 2)
void gconv_kernel(const ushort* __restrict__ Hnc, const ushort* __restrict__ X1,
                  const ushort* __restrict__ X2, const ushort* __restrict__ Wgp,
                  const float* __restrict__ binv, const float* __restrict__ bfold,
                  int layer, ushort* __restrict__ Hcv_out, ushort* __restrict__ Hnc_out) {
    __shared__ __align__(16) ushort At[2][256*32], Bt[2][128*32];
    int b = blockIdx.y;
    int n0 = blockIdx.x*128;
    size_t boff = (size_t)b*RS;
    const ushort* src0 = Hnc + boff;
    const ushort* src1 = X1 + boff;
    const ushort* src2 = X2 + boff;
    const ushort* wbase = Wgp + (size_t)layer*3*RS;
    int tid = threadIdx.x, lane = tid & 63, wid = tid >> 6;
    int wm = wid >> 1, wn = wid & 1;
    int frow = lane & 15, fko = (lane >> 4)*8;

    f4 acc[4][4];
    #pragma unroll
    for (int i = 0; i < 4; ++i)
        #pragma unroll
        for (int j = 0; j < 4; ++j) acc[i][j] = (f4)0.f;

    stage512<2>(At[0], wbase, 0, 207, 0, tid);
    stage512<1>(Bt[0], src0,  n0, 207, 0, tid);

    const int NK = 3*KSTEPS;
    for (int ks = 0; ks < NK; ++ks) {
        int cur = ks & 1;
        if (ks + 1 < NK) {
            int ks1 = ks + 1;
            const ushort* bs = (ks1 < KSTEPS) ? src0 : ((ks1 < 2*KSTEPS) ? src1 : src2);
            int kk = ks1 % KSTEPS;
            stage512<2>(At[cur^1], wbase + (size_t)(ks1/KSTEPS)*RS, 0, 207, kk*32, tid);
            stage512<1>(Bt[cur^1], bs, n0, 207, kk*32, tid);
            WAIT_VM(3);
        } else {
            WAIT_VM(0);
        }
        __builtin_amdgcn_s_barrier();
        s8v a[4], bf[4];
        #pragma unroll
        for (int f = 0; f < 4; ++f) {
            a[f]  = *(const s8v*)&At[cur][(wm*64 + f*16 + frow)*32 + fko];
            bf[f] = *(const s8v*)&Bt[cur][(wn*64 + f*16 + frow)*32 + fko];
        }
        #pragma unroll
        for (int fm = 0; fm < 4; ++fm)
            #pragma unroll
            for (int fn = 0; fn < 4; ++fn)
                acc[fm][fn] = __builtin_amdgcn_mfma_f32_16x16x32_bf16(bf[fn], a[fm], acc[fm][fn], 0, 0, 0);
        WAIT_LGKM0;
        __builtin_amdgcn_s_barrier();
    }

    ushort* Ocv = Hcv_out + boff;
    ushort* Onc = Hnc_out + boff;
    const float* bi  = binv  + layer*ROWS;
    const float* bsh = bfold + layer*ROWS;
    int g4 = (lane >> 4)*4;
    #pragma unroll
    for (int fm = 0; fm < 4; ++fm) {
        int o = wm*64 + fm*16 + (lane & 15);
        if (o >= ROWS) continue;
        float iv = bi[o], sh = bsh[o];              // o==207 -> 0 -> zero row/col
        #pragma unroll
        for (int fn = 0; fn < 4; ++fn) {
            int nq = n0 + wn*64 + fn*16 + g4;
            if (nq >= STRIDE) continue;
            f4 h = acc[fm][fn]*iv + sh;
            u16x4 hq = packbf4(h);
            *(u16x4*)(Ocv + (size_t)o*STRIDE + nq) = hq;
            #pragma unroll
            for (int r = 0; r < 4; ++r) {
                int n = nq + r;
                if (n < ROWS) Onc[(size_t)n*STRIDE + o] = hq[r];
            }
        }
    }
}

// ---------------------------------------------------------------------------
// final: out[b][n][o] = sum_c Hnc[n][c]*Wm[o][c] + bm[o]
// One block per (n-tile, batch): all 512 o columns, A (Hnc) staged once.
// 8 waves: wo=wid>>1 (o range of 128), wn=wid&1 (n half of 64).
// ---------------------------------------------------------------------------
__global__ __launch_bounds__(512, 2)
void final_kernel(const ushort* __restrict__ Hnc, const ushort* __restrict__ Wmp,
                  const float* __restrict__ bm, float* __restrict__ out) {
    __shared__ __align__(16) ushort At[2][128*32], Bt[2][512*32];
    int b = blockIdx.y;
    int n0 = blockIdx.x*128;
    const ushort* Hb = Hnc + (size_t)b*RS;
    int tid = threadIdx.x, lane = tid & 63, wid = tid >> 6;
    int wo = wid >> 1, wn = wid & 1;
    int frow = lane & 15, fko = (lane >> 4)*8;

    f4 acc[4][8];
    #pragma unroll
    for (int i = 0; i < 4; ++i)
        #pragma unroll
        for (int j = 0; j < 8; ++j) acc[i][j] = (f4)0.f;

    stage512<1>(At[0], Hb,  n0, 207, 0, tid);
    stage512<4>(Bt[0], Wmp, 0, 511, 0, tid);

    for (int ks = 0; ks < KSTEPS; ++ks) {
        int cur = ks & 1;
        if (ks + 1 < KSTEPS) {
            int k1 = (ks + 1)*32;
            stage512<1>(At[cur^1], Hb,  n0, 207, k1, tid);
            stage512<4>(Bt[cur^1], Wmp, 0, 511, k1, tid);
            WAIT_VM(5);
        } else {
            WAIT_VM(0);
        }
        __builtin_amdgcn_s_barrier();
        s8v a[4], bf[8];
        #pragma unroll
        for (int f = 0; f < 4; ++f)
            a[f]  = *(const s8v*)&At[cur][(wn*64 + f*16 + frow)*32 + fko];
        #pragma unroll
        for (int f = 0; f < 8; ++f)
            bf[f] = *(const s8v*)&Bt[cur][(wo*128 + f*16 + frow)*32 + fko];
        #pragma unroll
        for (int fm = 0; fm < 4; ++fm)
            #pragma unroll
            for (int fn = 0; fn < 8; ++fn)
                acc[fm][fn] = __builtin_amdgcn_mfma_f32_16x16x32_bf16(bf[fn], a[fm], acc[fm][fn], 0, 0, 0);
        WAIT_LGKM0;
        __builtin_amdgcn_s_barrier();
    }

    int g4 = (lane >> 4)*4;
    #pragma unroll
    for (int fm = 0; fm < 4; ++fm) {
        int n = n0 + wn*64 + fm*16 + (lane & 15);
        if (n >= 207) continue;
        float* orow = out + ((size_t)b*207 + n)*CO;
        #pragma unroll
        for (int fn = 0; fn < 8; ++fn) {
            int oq = wo*128 + fn*16 + g4;           // < 512 always, 4-aligned
            f4 bias = *(const f4*)(bm + oq);
            f4 v = acc[fm][fn] + bias;
            *(f4*)(orow + oq) = v;
        }
    }
}

static inline size_t align_up(size_t v, size_t a) { return (v + a - 1) & ~(a - 1); }

extern "C" void kernel_launch(void* const* d_in, const int* in_sizes, int n_in,
                              void* d_out, int out_size, void* d_ws, size_t ws_size,
                              hipStream_t stream) {
    const float* x     = (const float*)d_in[0];
    const float* nv1   = (const float*)d_in[1];
    const float* nv2   = (const float*)d_in[2];
    const float* Wg    = (const float*)d_in[3];
    const float* bg    = (const float*)d_in[4];
    const float* gamma = (const float*)d_in[5];
    const float* beta  = (const float*)d_in[6];
    const float* rmean = (const float*)d_in[7];
    const float* rvar  = (const float*)d_in[8];
    const float* Wm    = (const float*)d_in[9];
    const float* bm    = (const float*)d_in[10];
    float* out = (float*)d_out;

    char* ws = (char*)d_ws;
    const size_t bufN = (size_t)B*RS*sizeof(ushort);   // 47.7 MB
    ushort* P1   = (ushort*)ws; ws += align_up((size_t)STRIDE*STRIDE*2, 512);
    ushort* P2   = (ushort*)ws; ws += align_up((size_t)STRIDE*STRIDE*2, 512);
    float* binv  = (float*)ws;  ws += align_up((size_t)NLAYERS*ROWS*4, 512);
    float* bfold = (float*)ws;  ws += align_up((size_t)NLAYERS*ROWS*4, 512);
    ushort* Wgp  = (ushort*)ws; ws += align_up((size_t)NLAYERS*3*RS*2, 512);
    ushort* Wmp  = (ushort*)ws; ws += align_up((size_t)CO*STRIDE*2, 512);
    ushort* A0 = (ushort*)ws; ws += align_up(bufN, 512);   // Hcv ping
    ushort* A1 = (ushort*)ws; ws += align_up(bufN, 512);   // Hnc ping
    ushort* B0 = (ushort*)ws; ws += align_up(bufN, 512);   // Hcv pong
    ushort* B1 = (ushort*)ws; ws += align_up(bufN, 512);   // Hnc pong
    ushort* X1 = (ushort*)ws; ws += align_up(bufN, 512);
    ushort* X2 = (ushort*)ws; ws += align_up(bufN, 512);

    // --- prep ---
    adp_kernel<<<STRIDE, 256, 0, stream>>>(nv1, nv2, P1);
    p2_kernel<<<dim3(14, 14), dim3(16, 16), 0, stream>>>(P1, P2);
    bn_kernel<<<(NLAYERS*ROWS + 255)/256, 256, 0, stream>>>(gamma, beta, rmean, rvar, bg, binv, bfold);
    wg_prep<<<(NLAYERS*3*ROWS*STRIDE + 255)/256, 256, 0, stream>>>(Wg, Wgp);
    wm_prep<<<(CO*STRIDE + 255)/256, 256, 0, stream>>>(Wm, Wmp);
    h0_kernel<<<dim3(7, 7, B), dim3(32, 8), 0, stream>>>(x, A0, A1);

    // --- layer 0 ---
    diffuse_kernel<<<dim3(2, B), 512, 0, stream>>>(A0, P1, P2, X1, X2);
    gconv_kernel<<<dim3(2, B), 512, 0, stream>>>(A1, X1, X2, Wgp, binv, bfold, 0, B0, B1);

    // --- layer 1 ---
    diffuse_kernel<<<dim3(2, B), 512, 0, stream>>>(B0, P1, P2, X1, X2);
    gconv_kernel<<<dim3(2, B), 512, 0, stream>>>(B1, X1, X2, Wgp, binv, bfold, 1, A0, A1);

    // --- final ---
    final_kernel<<<dim3(2, B), 512, 0, stream>>>(A1, Wmp, bm, out);
}

// Round 7
// 362.548 us; speedup vs baseline: 12.6446x; 1.3406x over previous
//
#include <hip/hip_runtime.h>
#include <hip/hip_bf16.h>

#define B 512
#define N 207
#define C 207
#define CO 512
#define NLAYERS 2
#define EPS 1e-5f

#define STRIDE 224      // padded inner dim (elements)
#define ROWS 208        // padded row count for H-class buffers
#define KSTEPS 7        // 224/32
#define RS ((size_t)ROWS*STRIDE)
#define XSTR 232        // X1/X2 LDS row stride (mult of 8; 2-way bank spread)

typedef unsigned short ushort;
typedef short s8v __attribute__((ext_vector_type(8)));
typedef float f4 __attribute__((ext_vector_type(4)));
typedef unsigned short u16x4 __attribute__((ext_vector_type(4)));

__device__ __forceinline__ ushort f2bu(float f) {
    __hip_bfloat16 h = __float2bfloat16(f);
    return __builtin_bit_cast(ushort, h);
}
__device__ __forceinline__ float bu2f(ushort u) {
    union { unsigned int u; float f; } v; v.u = ((unsigned int)u) << 16;
    return v.f;
}
__device__ __forceinline__ u16x4 packbf4(f4 v) {
    u16x4 r;
    #pragma unroll
    for (int i = 0; i < 4; ++i) r[i] = f2bu(v[i]);
    return r;
}

// ---------------------------------------------------------------------------
// P1[w][v] = softmax_j(relu(nv1[w,:]@nv2[:,j]))[v]  (row-major, bf16, 224x224
// zero-padded). One block per row w.
// ---------------------------------------------------------------------------
__global__ void adp_kernel(const float* __restrict__ nv1, const float* __restrict__ nv2,
                           ushort* __restrict__ P1) {
    int w = blockIdx.x, j = threadIdx.x;
    __shared__ float red[256];
    if (w >= 207) {
        if (j < STRIDE) P1[w*STRIDE + j] = 0;
        return;
    }
    float val = 0.f;
    if (j < 207) {
        float acc = 0.f;
        #pragma unroll
        for (int k = 0; k < 10; ++k) acc += nv1[w*10 + k] * nv2[k*207 + j];
        val = fmaxf(acc, 0.f);
    }
    red[j] = (j < 207) ? val : -1e30f;
    __syncthreads();
    for (int off = 128; off > 0; off >>= 1) {
        if (j < off) red[j] = fmaxf(red[j], red[j+off]);
        __syncthreads();
    }
    float m = red[0];
    __syncthreads();
    float e = (j < 207) ? expf(val - m) : 0.f;
    red[j] = e;
    __syncthreads();
    for (int off = 128; off > 0; off >>= 1) {
        if (j < off) red[j] += red[j+off];
        __syncthreads();
    }
    float inv = 1.f / red[0];
    if (j < STRIDE) P1[w*STRIDE + j] = f2bu(e * inv);
}

// P2 = P1 @ P1
__global__ void p2_kernel(const ushort* __restrict__ P1, ushort* __restrict__ P2) {
    int v = blockIdx.x*16 + threadIdx.x;
    int w = blockIdx.y*16 + threadIdx.y;
    if (w < STRIDE && v < STRIDE) {
        float acc = 0.f;
        for (int u = 0; u < 207; ++u) acc += bu2f(P1[w*STRIDE + u]) * bu2f(P1[u*STRIDE + v]);
        P2[w*STRIDE + v] = f2bu(acc);
    }
}

// BN fold, padded: binv[o>=207]=0, bfold[o>=207]=0
__global__ void bn_kernel(const float* __restrict__ gamma, const float* __restrict__ beta,
                          const float* __restrict__ rmean, const float* __restrict__ rvar,
                          const float* __restrict__ bg,
                          float* __restrict__ binv, float* __restrict__ bfold) {
    int i = blockIdx.x*256 + threadIdx.x;
    if (i >= NLAYERS*ROWS) return;
    int l = i / ROWS, o = i % ROWS;
    float iv = 0.f, bf = 0.f;
    if (o < 207) {
        float g = gamma[l*207 + o];
        iv = g * rsqrtf(rvar[l*207 + o] + EPS);
        bf = bg[l*207 + o]*iv + beta[l*207 + o] - rmean[l*207 + o]*iv;
    }
    binv[i] = iv; bfold[i] = bf;
}

// Wg (L,207,621) f32 -> Wgp (L,3,208,224) bf16 zero-padded
__global__ void wg_prep(const float* __restrict__ Wg, ushort* __restrict__ Wgp) {
    int idx = blockIdx.x*256 + threadIdx.x;
    if (idx >= NLAYERS*3*ROWS*STRIDE) return;
    int k = idx % STRIDE;
    int o = (idx / STRIDE) % ROWS;
    int seg = (idx / (STRIDE*ROWS)) % 3;
    int l = idx / (STRIDE*ROWS*3);
    float v = (o < 207 && k < 207) ? Wg[((size_t)(l*207 + o))*621 + seg*207 + k] : 0.f;
    Wgp[idx] = f2bu(v);
}

// Wm (512,207) f32 -> Wmp (512,224) bf16 zero-padded
__global__ void wm_prep(const float* __restrict__ Wm, ushort* __restrict__ Wmp) {
    int idx = blockIdx.x*256 + threadIdx.x;
    if (idx >= CO*STRIDE) return;
    int k = idx % STRIDE, o = idx / STRIDE;
    Wmp[idx] = f2bu(k < 207 ? Wm[o*207 + k] : 0.f);
}

// x (B,207,207) f32 -> Hcv [c][n]  AND  Hnc [n][c]  (both 208x224, zero-padded)
__global__ void h0_kernel(const float* __restrict__ x, ushort* __restrict__ Hcv,
                          ushort* __restrict__ Hnc) {
    __shared__ float t[32][33];
    int b = blockIdx.z;
    int n0 = blockIdx.x*32, c0 = blockIdx.y*32;
    int tx = threadIdx.x, ty = threadIdx.y;
    for (int i = ty; i < 32; i += 8) {
        int n = n0 + i, c = c0 + tx;
        t[i][tx] = (n < 207 && c < 207) ? x[((size_t)b*207 + n)*207 + c] : 0.f;
    }
    __syncthreads();
    size_t base = (size_t)b*RS;
    for (int i = ty; i < 32; i += 8) {
        int n = n0 + i, c = c0 + tx;
        if (n < ROWS && c < STRIDE) Hnc[base + (size_t)n*STRIDE + c] = f2bu(t[i][tx]);
    }
    for (int i = ty; i < 32; i += 8) {
        int c = c0 + i, n = n0 + tx;
        if (c < ROWS && n < STRIDE) Hcv[base + (size_t)c*STRIDE + n] = f2bu(t[tx][i]);
    }
}

// ---------------------------------------------------------------------------
// async staging for 512-thread blocks: ROUNDS_*128 rows x 32 cols bf16 tile
// via global_load_lds (16B/lane, wave-uniform LDS base + lane*16B).
// rows clamped to rmax (clamped rows must be zero/benign rows in src).
// ---------------------------------------------------------------------------
template<int ROUNDS_>
__device__ __forceinline__ void stage512(ushort* __restrict__ tile,
                                         const ushort* __restrict__ src,
                                         int rbase, int rmax, int kbase, int tid) {
    int lane = tid & 63, wave = tid >> 6;   // 8 waves
    #pragma unroll
    for (int i = 0; i < ROUNDS_; ++i) {
        int r = rbase + i*128 + wave*16 + (lane >> 2);
        r = (r > rmax) ? rmax : r;
        const ushort* g = src + (size_t)r*STRIDE + kbase + (lane & 3)*8;
        ushort* l = tile + i*4096 + wave*512;          // wave-uniform base
        __builtin_amdgcn_global_load_lds(
            (const __attribute__((address_space(1))) void*)g,
            (__attribute__((address_space(3))) void*)l, 16, 0, 0);
    }
}

#define WAIT_VM(n) asm volatile("s_waitcnt vmcnt(" #n ")" ::: "memory")
#define WAIT_LGKM0 asm volatile("s_waitcnt lgkmcnt(0)" ::: "memory")

// ---------------------------------------------------------------------------
// layer_kernel: one block per (128-node slab, batch).
// Phase 1 (diffuse): X1 = P1*Hcv^K, X2 = P2*Hcv^K for this slab's 128 rows,
//   all 224 channels -> kept in LDS (stride XSTR bf16), never hits HBM.
// Phase 2 (gconv): G[o][n] = Wg1*X1 + Wg2*X2 + Wg0*Hnc, BN-folded,
//   dual-layout store (Hcv' quads + Hnc' scatter). Seg order [1,2,0] lets the
//   Hnc staging dbuf alias the dead X1 region.
// ---------------------------------------------------------------------------
__global__ __launch_bounds__(512, 2)
void layer_kernel(const ushort* __restrict__ Hcv, const ushort* __restrict__ Hnc,
                  const ushort* __restrict__ P1, const ushort* __restrict__ P2,
                  const ushort* __restrict__ Wgl,
                  const float* __restrict__ bi, const float* __restrict__ bsh,
                  ushort* __restrict__ Hcv_out, ushort* __restrict__ Hnc_out) {
    __shared__ __align__(16) ushort lds[75776];          // 148 KB
    ushort* X1l = lds;                  // 128*XSTR = 29696
    ushort* X2l = lds + 29696;          // 29696
    ushort* Wgt = lds + 59392;          // 2*8192 (256x32 dbuf)
    ushort* A1t = lds;                  // phase1 alias: 2*4096 (128x32 dbuf)
    ushort* A2t = lds + 8192;           // phase1 alias: 2*4096
    ushort* Bt  = lds + 16384;          // phase1 alias: 2*8192 (256x32 dbuf)
    ushort* Hnct = lds;                 // seg0 alias over dead X1l: 2*4096

    int tile = blockIdx.x;              // 0/1
    int b = blockIdx.y;
    int n0 = tile*128;
    size_t boff = (size_t)b*RS;
    const ushort* Hcvb = Hcv + boff;
    const ushort* Hncb = Hnc + boff;

    int tid = threadIdx.x, lane = tid & 63, wid = tid >> 6;
    int frow = lane & 15, fko = (lane >> 4)*8, g4 = (lane >> 4)*4;

    // ================= phase 1: diffuse into LDS =================
    int wmA = wid >> 1, wnA = wid & 1;   // wmA: 32 w-rows (2 frags); wnA: 128 c (8 frags)
    f4 aX1[2][8], aX2[2][8];
    #pragma unroll
    for (int i = 0; i < 2; ++i)
        #pragma unroll
        for (int j = 0; j < 8; ++j) { aX1[i][j] = (f4)0.f; aX2[i][j] = (f4)0.f; }

    stage512<1>(A1t, P1, n0, 223, 0, tid);
    stage512<1>(A2t, P2, n0, 223, 0, tid);
    stage512<2>(Bt,  Hcvb, 0, 207, 0, tid);

    for (int ks = 0; ks < KSTEPS; ++ks) {
        int cur = ks & 1;
        if (ks + 1 < KSTEPS) {
            int k1 = (ks + 1)*32;
            stage512<1>(A1t + (cur^1)*4096, P1, n0, 223, k1, tid);
            stage512<1>(A2t + (cur^1)*4096, P2, n0, 223, k1, tid);
            stage512<2>(Bt  + (cur^1)*8192, Hcvb, 0, 207, k1, tid);
            WAIT_VM(4);
        } else {
            stage512<2>(Wgt, Wgl + RS, 0, 207, 0, tid);   // phase-2 prologue (seg1,k=0)
            WAIT_VM(2);
        }
        __builtin_amdgcn_s_barrier();
        s8v a1[2], a2[2], bfr[8];
        #pragma unroll
        for (int f = 0; f < 2; ++f) {
            a1[f] = *(const s8v*)&A1t[cur*4096 + (wmA*32 + f*16 + frow)*32 + fko];
            a2[f] = *(const s8v*)&A2t[cur*4096 + (wmA*32 + f*16 + frow)*32 + fko];
        }
        #pragma unroll
        for (int f = 0; f < 8; ++f)
            bfr[f] = *(const s8v*)&Bt[cur*8192 + (wnA*128 + f*16 + frow)*32 + fko];
        #pragma unroll
        for (int fm = 0; fm < 2; ++fm)
            #pragma unroll
            for (int fn = 0; fn < 8; ++fn) {
                aX1[fm][fn] = __builtin_amdgcn_mfma_f32_16x16x32_bf16(bfr[fn], a1[fm], aX1[fm][fn], 0, 0, 0);
                aX2[fm][fn] = __builtin_amdgcn_mfma_f32_16x16x32_bf16(bfr[fn], a2[fm], aX2[fm][fn], 0, 0, 0);
            }
        WAIT_LGKM0;
        __builtin_amdgcn_s_barrier();
    }
    // phase-1 epilogue: X fragments -> LDS (staging regions now dead)
    #pragma unroll
    for (int fm = 0; fm < 2; ++fm) {
        int w = wmA*32 + fm*16 + (lane & 15);            // 0..127
        #pragma unroll
        for (int fn = 0; fn < 8; ++fn) {
            int cq = wnA*128 + fn*16 + g4;
            if (cq < STRIDE) {
                *(u16x4*)&X1l[w*XSTR + cq] = packbf4(aX1[fm][fn]);
                *(u16x4*)&X2l[w*XSTR + cq] = packbf4(aX2[fm][fn]);
            }
        }
    }
    WAIT_LGKM0;
    __builtin_amdgcn_s_barrier();

    // ================= phase 2: gconv (segs 1,2,0) =================
    int wmB = wid >> 2, wnB = wid & 3;   // wmB: 128 o-rows (8 frags); wnB: 32 n (2 frags)
    f4 aG[8][2];
    #pragma unroll
    for (int i = 0; i < 8; ++i)
        #pragma unroll
        for (int j = 0; j < 2; ++j) aG[i][j] = (f4)0.f;

    const int NK = 3*KSTEPS;
    for (int ks = 0; ks < NK; ++ks) {
        int cur = ks & 1;
        int seg = (ks < 7) ? 1 : (ks < 14) ? 2 : 0;
        int k0 = (ks % 7)*32;
        if (ks + 1 < NK) {
            int ks1 = ks + 1;
            int seg1v = (ks1 < 7) ? 1 : (ks1 < 14) ? 2 : 0;
            int kk1 = (ks1 % 7)*32;
            stage512<2>(Wgt + (cur^1)*8192, Wgl + (size_t)seg1v*RS, 0, 207, kk1, tid);
            if (seg1v == 0) {
                stage512<1>(Hnct + (cur^1)*4096, Hncb, n0, 207, kk1, tid);
                WAIT_VM(3);
            } else {
                WAIT_VM(2);
            }
        } else {
            WAIT_VM(0);
        }
        __builtin_amdgcn_s_barrier();
        s8v a[8], bfr[2];
        #pragma unroll
        for (int f = 0; f < 8; ++f)
            a[f] = *(const s8v*)&Wgt[cur*8192 + (wmB*128 + f*16 + frow)*32 + fko];
        if (seg == 0) {
            #pragma unroll
            for (int fn = 0; fn < 2; ++fn)
                bfr[fn] = *(const s8v*)&Hnct[cur*4096 + (wnB*32 + fn*16 + frow)*32 + fko];
        } else {
            const ushort* Xs = (seg == 1) ? X1l : X2l;
            #pragma unroll
            for (int fn = 0; fn < 2; ++fn) {
                int row = wnB*32 + fn*16 + frow;
                bfr[fn] = *(const s8v*)&Xs[row*XSTR + k0 + fko];
            }
        }
        #pragma unroll
        for (int fm = 0; fm < 8; ++fm)
            #pragma unroll
            for (int fn = 0; fn < 2; ++fn)
                aG[fm][fn] = __builtin_amdgcn_mfma_f32_16x16x32_bf16(bfr[fn], a[fm], aG[fm][fn], 0, 0, 0);
        WAIT_LGKM0;
        __builtin_amdgcn_s_barrier();
    }

    // phase-2 epilogue: BN fold + dual-layout store
    ushort* Ocv = Hcv_out + boff;
    ushort* Onc = Hnc_out + boff;
    #pragma unroll
    for (int fm = 0; fm < 8; ++fm) {
        int o = wmB*128 + fm*16 + (lane & 15);
        if (o >= ROWS) continue;
        float iv = bi[o], sh = bsh[o];                   // o==207 -> 0 -> zero row
        #pragma unroll
        for (int fn = 0; fn < 2; ++fn) {
            int nq = n0 + wnB*32 + fn*16 + g4;
            if (nq >= STRIDE) continue;
            f4 h = aG[fm][fn]*iv + sh;
            u16x4 hq = packbf4(h);
            *(u16x4*)(Ocv + (size_t)o*STRIDE + nq) = hq;
            #pragma unroll
            for (int r = 0; r < 4; ++r) {
                int n = nq + r;
                if (n < ROWS) Onc[(size_t)n*STRIDE + o] = hq[r];
            }
        }
    }
}

// ---------------------------------------------------------------------------
// final: out[b][n][o] = sum_c Hnc[n][c]*Wm[o][c] + bm[o]
// One block per (n-tile, batch): all 512 o columns, A (Hnc) staged once.
// ---------------------------------------------------------------------------
__global__ __launch_bounds__(512, 2)
void final_kernel(const ushort* __restrict__ Hnc, const ushort* __restrict__ Wmp,
                  const float* __restrict__ bm, float* __restrict__ out) {
    __shared__ __align__(16) ushort At[2][128*32], Bt[2][512*32];
    int b = blockIdx.y;
    int n0 = blockIdx.x*128;
    const ushort* Hb = Hnc + (size_t)b*RS;
    int tid = threadIdx.x, lane = tid & 63, wid = tid >> 6;
    int wo = wid >> 1, wn = wid & 1;
    int frow = lane & 15, fko = (lane >> 4)*8;

    f4 acc[4][8];
    #pragma unroll
    for (int i = 0; i < 4; ++i)
        #pragma unroll
        for (int j = 0; j < 8; ++j) acc[i][j] = (f4)0.f;

    stage512<1>(At[0], Hb,  n0, 207, 0, tid);
    stage512<4>(Bt[0], Wmp, 0, 511, 0, tid);

    for (int ks = 0; ks < KSTEPS; ++ks) {
        int cur = ks & 1;
        if (ks + 1 < KSTEPS) {
            int k1 = (ks + 1)*32;
            stage512<1>(At[cur^1], Hb,  n0, 207, k1, tid);
            stage512<4>(Bt[cur^1], Wmp, 0, 511, k1, tid);
            WAIT_VM(5);
        } else {
            WAIT_VM(0);
        }
        __builtin_amdgcn_s_barrier();
        s8v a[4], bf[8];
        #pragma unroll
        for (int f = 0; f < 4; ++f)
            a[f]  = *(const s8v*)&At[cur][(wn*64 + f*16 + frow)*32 + fko];
        #pragma unroll
        for (int f = 0; f < 8; ++f)
            bf[f] = *(const s8v*)&Bt[cur][(wo*128 + f*16 + frow)*32 + fko];
        #pragma unroll
        for (int fm = 0; fm < 4; ++fm)
            #pragma unroll
            for (int fn = 0; fn < 8; ++fn)
                acc[fm][fn] = __builtin_amdgcn_mfma_f32_16x16x32_bf16(bf[fn], a[fm], acc[fm][fn], 0, 0, 0);
        WAIT_LGKM0;
        __builtin_amdgcn_s_barrier();
    }

    int g4 = (lane >> 4)*4;
    #pragma unroll
    for (int fm = 0; fm < 4; ++fm) {
        int n = n0 + wn*64 + fm*16 + (lane & 15);
        if (n >= 207) continue;
        float* orow = out + ((size_t)b*207 + n)*CO;
        #pragma unroll
        for (int fn = 0; fn < 8; ++fn) {
            int oq = wo*128 + fn*16 + g4;           // < 512 always, 4-aligned
            f4 bias = *(const f4*)(bm + oq);
            f4 v = acc[fm][fn] + bias;
            *(f4*)(orow + oq) = v;
        }
    }
}

static inline size_t align_up(size_t v, size_t a) { return (v + a - 1) & ~(a - 1); }

extern "C" void kernel_launch(void* const* d_in, const int* in_sizes, int n_in,
                              void* d_out, int out_size, void* d_ws, size_t ws_size,
                              hipStream_t stream) {
    const float* x     = (const float*)d_in[0];
    const float* nv1   = (const float*)d_in[1];
    const float* nv2   = (const float*)d_in[2];
    const float* Wg    = (const float*)d_in[3];
    const float* bg    = (const float*)d_in[4];
    const float* gamma = (const float*)d_in[5];
    const float* beta  = (const float*)d_in[6];
    const float* rmean = (const float*)d_in[7];
    const float* rvar  = (const float*)d_in[8];
    const float* Wm    = (const float*)d_in[9];
    const float* bm    = (const float*)d_in[10];
    float* out = (float*)d_out;

    char* ws = (char*)d_ws;
    const size_t bufN = (size_t)B*RS*sizeof(ushort);   // 47.7 MB
    ushort* P1   = (ushort*)ws; ws += align_up((size_t)STRIDE*STRIDE*2, 512);
    ushort* P2   = (ushort*)ws; ws += align_up((size_t)STRIDE*STRIDE*2, 512);
    float* binv  = (float*)ws;  ws += align_up((size_t)NLAYERS*ROWS*4, 512);
    float* bfold = (float*)ws;  ws += align_up((size_t)NLAYERS*ROWS*4, 512);
    ushort* Wgp  = (ushort*)ws; ws += align_up((size_t)NLAYERS*3*RS*2, 512);
    ushort* Wmp  = (ushort*)ws; ws += align_up((size_t)CO*STRIDE*2, 512);
    ushort* A0 = (ushort*)ws; ws += align_up(bufN, 512);   // Hcv ping
    ushort* A1 = (ushort*)ws; ws += align_up(bufN, 512);   // Hnc ping
    ushort* B0 = (ushort*)ws; ws += align_up(bufN, 512);   // Hcv pong
    ushort* B1 = (ushort*)ws; ws += align_up(bufN, 512);   // Hnc pong

    // --- prep ---
    adp_kernel<<<STRIDE, 256, 0, stream>>>(nv1, nv2, P1);
    p2_kernel<<<dim3(14, 14), dim3(16, 16), 0, stream>>>(P1, P2);
    bn_kernel<<<(NLAYERS*ROWS + 255)/256, 256, 0, stream>>>(gamma, beta, rmean, rvar, bg, binv, bfold);
    wg_prep<<<(NLAYERS*3*ROWS*STRIDE + 255)/256, 256, 0, stream>>>(Wg, Wgp);
    wm_prep<<<(CO*STRIDE + 255)/256, 256, 0, stream>>>(Wm, Wmp);
    h0_kernel<<<dim3(7, 7, B), dim3(32, 8), 0, stream>>>(x, A0, A1);

    // --- layer 0 ---
    layer_kernel<<<dim3(2, B), 512, 0, stream>>>(A0, A1, P1, P2,
        Wgp, binv, bfold, B0, B1);
    // --- layer 1 ---
    layer_kernel<<<dim3(2, B), 512, 0, stream>>>(B0, B1, P1, P2,
        Wgp + (size_t)3*RS, binv + ROWS, bfold + ROWS, A0, A1);

    // --- final ---
    final_kernel<<<dim3(2, B), 512, 0, stream>>>(A1, Wmp, bm, out);
}